// Round 4
// baseline (402.586 us; speedup 1.0000x reference)
//
#include <hip/hip_runtime.h>
#include <hip/hip_bf16.h>

// Problem constants
constexpr int kB   = 2;
constexpr int kH   = 8;
constexpr int kG   = 4;
constexpr int kS   = 14;
constexpr int kSS  = 196;   // S*S
constexpr int kKey = 784;   // G*S*S keys per (b,h)
constexpr int kMid = 96;
constexpr float kScl = 0.10206207261596577f; // 1/sqrt(96)
constexpr float kK2  = 0.14724663682f;       // kScl / ln(2)  (exp2 domain)
constexpr float kCc  = 11.5415603272f;       // 8 nats / ln(2): constant softmax shift (exact)

// ---------------- workspace layout (float elements) ----------------
constexpr size_t SZ_QKV = (size_t)kB*kH*kG*kSS*kMid;   // 1,204,224
constexpr size_t OFF_Q  = 0;
constexpr size_t OFF_K  = OFF_Q + SZ_QKV;              // K stored CHANNEL-MAJOR: [bh][c][key784]
constexpr size_t OFF_V  = OFF_K + SZ_QKV;
constexpr size_t OFF_FR = OFF_V + SZ_QKV;              // 27*32 row table
constexpr size_t OFF_FC = OFF_FR + 27*32;              // 27*32 col table
constexpr size_t OFF_PS = OFF_FC + 27*32;              // Psum
constexpr size_t SZ_PS  = (size_t)kB*kH*kG*kSS*kKey;   // 9,834,496
constexpr size_t OFF_VO = OFF_PS + SZ_PS;              // vo: 1,204,224

// ============================================================
// Kernel 1: embed tables. row_rel/col_rel only take values n/13, n in [-13,13],
// so the whole (G,S,S,S,S,32) embed tensors reduce to two 27x32 tables.
// ============================================================
__global__ void k_tables(const float* __restrict__ rw1, const float* __restrict__ rb1,
                         const float* __restrict__ rgam, const float* __restrict__ rbet,
                         const float* __restrict__ rw2, const float* __restrict__ rb2,
                         const float* __restrict__ cw1, const float* __restrict__ cb1,
                         const float* __restrict__ cgam, const float* __restrict__ cbet,
                         const float* __restrict__ cw2, const float* __restrict__ cb2,
                         float* __restrict__ frow, float* __restrict__ fcol) {
  int t = threadIdx.x;
  if (t >= 54) return;
  int which = t / 27;
  int n = t % 27;
  float tv = (float)(n - 13) / 13.0f;
  const float* w1  = which ? cw1  : rw1;
  const float* b1  = which ? cb1  : rb1;
  const float* gam = which ? cgam : rgam;
  const float* bet = which ? cbet : rbet;
  const float* w2  = which ? cw2  : rw2;
  const float* b2  = which ? cb2  : rb2;
  float h[16];
  float mu = 0.f;
#pragma unroll
  for (int d = 0; d < 16; ++d) { h[d] = tv * w1[d] + b1[d]; mu += h[d]; }
  mu *= (1.0f/16.0f);
  float var = 0.f;
#pragma unroll
  for (int d = 0; d < 16; ++d) { float z = h[d] - mu; var += z*z; }
  var *= (1.0f/16.0f);
  float rstd = rsqrtf(var + 1e-5f);
#pragma unroll
  for (int d = 0; d < 16; ++d) {
    float z = (h[d] - mu) * rstd * gam[d] + bet[d];
    h[d] = z / (1.0f + expf(-z));   // silu
  }
  float* outp = (which ? fcol : frow) + n*32;
  for (int c = 0; c < 32; ++c) {
    float o = b2[c];
#pragma unroll
    for (int d = 0; d < 16; ++d) o += h[d] * w2[d*32 + c];
    outp[c] = o;
  }
}

// ============================================================
// Kernel 2: QKV projection (unchanged from R3).
// Q,V layout: [b][h][g][ij][c] (c contiguous).  K layout: CHANNEL-MAJOR
// [b][h][c][g*196+ij]. d = c*8 + h per the reference reshape(MID, HEADS).
// ============================================================
__global__ __launch_bounds__(256)
void k_qkv(const float* __restrict__ x,
           const float* __restrict__ Wq, const float* __restrict__ bq,
           const float* __restrict__ Wk, const float* __restrict__ bk,
           const float* __restrict__ Wv, const float* __restrict__ bv,
           float* __restrict__ Q, float* __restrict__ K, float* __restrict__ V) {
  const int bid = blockIdx.x;
  const int ten = blockIdx.y;
  const int i = bid % 14;
  const int g = (bid / 14) % 4;
  const int b = bid / 56;
  const float* W    = (ten == 0) ? Wq : (ten == 1) ? Wk : Wv;
  const float* bias = (ten == 0) ? bq : (ten == 1) ? bk : bv;
  float* O          = (ten == 0) ? Q  : (ten == 1) ? K  : V;

  __shared__ float xs[96][14];
  for (int idx = threadIdx.x; idx < 96*14; idx += 256) {
    int cin = idx / 14, j = idx % 14;
    xs[cin][j] = x[((size_t)(b*96 + cin)*4 + g)*196 + i*14 + j];
  }
  __syncthreads();

  for (int d = threadIdx.x; d < 768; d += 256) {
    int c = d >> 3, h = d & 7;
    float bvv = bias[d];
    float acc[14];
#pragma unroll
    for (int j = 0; j < 14; ++j) acc[j] = bvv;
    const float* wrow = W + (size_t)d * 96;
    for (int cc = 0; cc < 96; cc += 4) {
      float4 w = *(const float4*)(wrow + cc);
#pragma unroll
      for (int j = 0; j < 14; ++j)
        acc[j] += w.x*xs[cc][j] + w.y*xs[cc+1][j] + w.z*xs[cc+2][j] + w.w*xs[cc+3][j];
    }
    if (ten == 1) {
      float* op = K + ((size_t)((b*8 + h)*96 + c))*784 + g*196 + i*14;
#pragma unroll
      for (int j = 0; j < 14; ++j) op[j] = acc[j];
    } else {
      float* op = O + ((size_t)((b*8 + h)*4 + g)*196 + i*14)*96 + c;
#pragma unroll
      for (int j = 0; j < 14; ++j) op[(size_t)j*96] = acc[j];
    }
  }
}

// ============================================================
// Kernel 3: fused content + bias + softmax (R3 math, quarter-split grid).
// Block = (b,h,i, jquarter): 16 query rows (4 g x 4 j, j-tail padded by
// clamping to row 13 -- padded rows are exact duplicates, never stored).
// 896 blocks, ~43 KB LDS -> 3 blocks/CU.
// ============================================================
__global__ __launch_bounds__(256, 3)
void k_attn(const float* __restrict__ Q, const float* __restrict__ Kt,
            const float* __restrict__ frow_g, const float* __restrict__ fcol_g,
            const float* __restrict__ gemb_g, float* __restrict__ Psum) {
  const int tid = threadIdx.x;
  const int bid = blockIdx.x;           // 224 = b*112 + h*14 + i
  const int jstart = blockIdx.y * 4;    // 0,4,8,12
  const int qi = bid % 14;
  const int hh = (bid / 14) % 8;
  const int bb = bid / 112;
  const int bh = bb*8 + hh;
  constexpr int NQ = 16;                // 4 g * 4 j (padded)

  __shared__ alignas(16) float qs[NQ][96];
  __shared__ alignas(16) float frowS[27*32];
  __shared__ alignas(16) float fcolS[27*32];
  __shared__ alignas(16) float gembS[128];
  __shared__ float Arr2[NQ][27];              // row bias dot, pre-scaled by kK2
  __shared__ float Acl2[NQ][27];              // col bias dot, pre-scaled by kK2
  __shared__ float AgE[NQ][4];                // exp2(group bias * kK2)
  __shared__ float AgErot[NQ][4];             // per-v rotated AgE
  __shared__ float redw[NQ][4];
  __shared__ float DinvS[NQ];
  __shared__ __hip_bfloat16 contl[NQ][kKey];  // E values: [q][m*196 + kl]

  // ---- stage queries + tables (tables pre-scaled into exp2 domain)
  for (int idx = tid; idx < NQ*96; idx += 256) {
    int q = idx / 96, c = idx - q*96;
    int g = q >> 2, jq = q & 3;
    int jj = jstart + jq; if (jj > 13) jj = 13;      // clamp pad rows
    qs[q][c] = Q[((size_t)((bh*4 + g)*kSS + qi*14 + jj))*96 + c];
  }
  for (int idx = tid; idx < 864; idx += 256) frowS[idx] = frow_g[idx] * kK2;
  for (int idx = tid; idx < 864; idx += 256) fcolS[idx] = fcol_g[idx] * kK2;
  if (tid < 128) gembS[tid] = gemb_g[tid] * kK2;
  __syncthreads();

  // ---- per-query bias tables (exp2 domain)
  for (int t = tid; t < NQ*58; t += 256) {
    int q = t / 58, s = t - q*58;
    float acc = 0.f;
    if (s < 27) {
#pragma unroll
      for (int c = 0; c < 32; ++c) acc += qs[q][c] * frowS[s*32 + c];
      Arr2[q][s] = acc;
    } else if (s < 54) {
      int n = s - 27;
#pragma unroll
      for (int c = 0; c < 32; ++c) acc += qs[q][32+c] * fcolS[n*32 + c];
      Acl2[q][n] = acc;
    } else {
      int p = s - 54;
#pragma unroll
      for (int c = 0; c < 32; ++c) acc += qs[q][64+c] * gembS[p*32 + c];
      AgE[q][p] = exp2f(acc);
    }
  }
  __syncthreads();

  // ---- content GEMM: thread owns key-col kl=tid (<196), all 4 m in registers.
  // K channel-major -> coalesced global loads; 16 FMA per ds_read_b128 of q.
  if (tid < 196) {
    const float* kb = Kt + (size_t)bh*96*784 + tid;
    for (int h2 = 0; h2 < 2; ++h2) {
      float acc[8][4];
#pragma unroll
      for (int q = 0; q < 8; ++q)
#pragma unroll
        for (int m = 0; m < 4; ++m) acc[q][m] = 0.f;
      for (int cc = 0; cc < 96; cc += 4) {
        float kf[4][4];
#pragma unroll
        for (int c = 0; c < 4; ++c)
#pragma unroll
          for (int m = 0; m < 4; ++m)
            kf[c][m] = kb[(size_t)(cc + c)*784 + m*196];
#pragma unroll
        for (int q = 0; q < 8; ++q) {
          float4 qv = *(const float4*)(&qs[h2*8 + q][cc]);
#pragma unroll
          for (int m = 0; m < 4; ++m)
            acc[q][m] += qv.x*kf[0][m] + qv.y*kf[1][m] + qv.z*kf[2][m] + qv.w*kf[3][m];
        }
      }
      // E = exp2(content*kK2 - Cc), scalar bf16 stores
#pragma unroll
      for (int q = 0; q < 8; ++q)
#pragma unroll
        for (int m = 0; m < 4; ++m)
          contl[h2*8 + q][m*196 + tid] = __float2bfloat16(exp2f(acc[q][m]*kK2 - kCc));
    }
  }
  __syncthreads();

  const int kk = (tid < 196) ? (tid / 14) : 0;
  const int ll = (tid < 196) ? (tid % 14) : 0;
  const int da = kk - qi;

  for (int v = 0; v < 4; ++v) {
    int s1a, s1b, s2a, s2b;
    if (v == 0)      { s1a = 1;  s1b = 0;  s2a = 0;  s2b = 1;  }
    else if (v == 1) { s1a = 0;  s1b = -1; s2a = 1;  s2b = 0;  }
    else if (v == 2) { s1a = -1; s1b = 0;  s2a = 0;  s2b = -1; }
    else             { s1a = 0;  s1b = 1;  s2a = -1; s2b = 0;  }

    if (tid < NQ*4) {
      int q = tid >> 2, m = tid & 3, gq = q >> 2;
      AgErot[q][m] = AgE[q][(m - gq + v + 8) & 3];
    }
    __syncthreads();

    // ---- pass B: denominators. Per-thread partial per q, shuffle-reduce.
    float arvE[NQ];
    float prt[NQ];
    if (tid < 196) {
#pragma unroll
      for (int gq = 0; gq < 4; ++gq) {
#pragma unroll
        for (int jq = 0; jq < 4; ++jq) {
          const int q = gq*4 + jq;
          int jj = jstart + jq; if (jj > 13) jj = 13;   // match clamped pad rows
          const int db = ll - jj;
          const int ai = s1a*da + s1b*db, ci = s2a*da + s2b*db;
          arvE[q] = exp2f(Arr2[q][13 + ai] + Acl2[q][13 + ci]);
          float e0 = __bfloat162float(contl[q][0*196 + tid]);
          float e1 = __bfloat162float(contl[q][1*196 + tid]);
          float e2 = __bfloat162float(contl[q][2*196 + tid]);
          float e3 = __bfloat162float(contl[q][3*196 + tid]);
          prt[q] = (e0*AgErot[q][0] + e1*AgErot[q][1] +
                    e2*AgErot[q][2] + e3*AgErot[q][3]) * arvE[q];
        }
      }
    } else {
#pragma unroll
      for (int q = 0; q < NQ; ++q) { prt[q] = 0.f; arvE[q] = 0.f; }
    }
#pragma unroll
    for (int q = 0; q < NQ; ++q) {
      float s = prt[q];
#pragma unroll
      for (int off = 1; off < 64; off <<= 1) s += __shfl_xor(s, off, 64);
      if ((tid & 63) == 0) redw[q][tid >> 6] = s;
    }
    __syncthreads();
    if (tid < NQ)
      DinvS[tid] = 1.0f / (redw[tid][0] + redw[tid][1] + redw[tid][2] + redw[tid][3]);
    __syncthreads();

    // ---- pass C: normalized probs (no transcendentals), summed over g
    if (tid < 196) {
      float* pbase = Psum + ((size_t)((bh*4 + v)*kSS + qi*14 + jstart))*kKey + tid;
#pragma unroll
      for (int jq = 0; jq < 4; ++jq) {
        if (jstart + jq >= 14) break;                  // pad rows never stored
        float am[4] = {0.f, 0.f, 0.f, 0.f};
#pragma unroll
        for (int gq = 0; gq < 4; ++gq) {
          const int q = gq*4 + jq;
          const float fq = arvE[q] * DinvS[q];
          float e0 = __bfloat162float(contl[q][0*196 + tid]);
          float e1 = __bfloat162float(contl[q][1*196 + tid]);
          float e2 = __bfloat162float(contl[q][2*196 + tid]);
          float e3 = __bfloat162float(contl[q][3*196 + tid]);
          am[0] += e0 * (AgErot[q][0] * fq);
          am[1] += e1 * (AgErot[q][1] * fq);
          am[2] += e2 * (AgErot[q][2] * fq);
          am[3] += e3 * (AgErot[q][3] * fq);
        }
        float* pp = pbase + (size_t)jq*kKey;
#pragma unroll
        for (int m = 0; m < 4; ++m) pp[m*196] = am[m];
      }
    }
    __syncthreads();   // protects AgErot for next v
  }
}

// ============================================================
// Kernel 4: PV GEMM. Per (b,h,v, ij-tile of 49): [49 x 784] @ [784 x 96].
// V staged TRANSPOSED (Vt[c][k]) so both P and V are read as float2 k-pairs
// (ds_read_b64): 10 b64 reads per 42 FMA vs 20 b32 before.
// ============================================================
__global__ __launch_bounds__(256)
void k_pv(const float* __restrict__ Psum, const float* __restrict__ V,
          float* __restrict__ vo) {
  const int tid = threadIdx.x;
  const int bid = blockIdx.x;
  const int itile = bid & 3;
  const int v = (bid >> 2) & 3;
  const int h = (bid >> 4) & 7;
  const int b = bid >> 7;
  const int bh = b*8 + h;

  __shared__ alignas(16) float Ps[49][196];
  __shared__ alignas(16) float Vt[96][196];   // transposed V tile
  const int rg = tid >> 5;          // 0..7 (rg<7 active: 7 rows each)
  const int c3 = (tid & 31) * 3;    // 0..93
  float acc[7][3];
#pragma unroll
  for (int r = 0; r < 7; ++r) { acc[r][0] = 0.f; acc[r][1] = 0.f; acc[r][2] = 0.f; }

  const float* prow = Psum + ((size_t)((bh*4 + v)*kSS + itile*49))*kKey;
  const float* vrow = V + (size_t)bh*kKey*96;

  for (int mc = 0; mc < 4; ++mc) {
    for (int idx = tid; idx < 49*196; idx += 256) {
      int r = idx / 196, k = idx - r*196;
      Ps[r][k] = prow[(size_t)r*kKey + mc*196 + k];
    }
    for (int idx = tid; idx < 196*96; idx += 256) {
      int k = idx / 96, c = idx - k*96;               // coalesced global read
      Vt[c][k] = vrow[(size_t)mc*196*96 + idx];       // transposed LDS write
    }
    __syncthreads();
    if (rg < 7) {
      for (int k = 0; k < 196; k += 2) {
        float2 v0 = *(const float2*)(&Vt[c3    ][k]);
        float2 v1 = *(const float2*)(&Vt[c3 + 1][k]);
        float2 v2 = *(const float2*)(&Vt[c3 + 2][k]);
#pragma unroll
        for (int rr = 0; rr < 7; ++rr) {
          float2 p = *(const float2*)(&Ps[rg*7 + rr][k]);
          acc[rr][0] += p.x*v0.x + p.y*v0.y;
          acc[rr][1] += p.x*v1.x + p.y*v1.y;
          acc[rr][2] += p.x*v2.x + p.y*v2.y;
        }
      }
    }
    __syncthreads();
  }
  if (rg < 7) {
#pragma unroll
    for (int rr = 0; rr < 7; ++rr) {
      int ij = itile*49 + rg*7 + rr;
      float* op = vo + ((size_t)((b*4 + v)*kSS + ij))*768 + h;
#pragma unroll
      for (int cc = 0; cc < 3; ++cc) op[(c3+cc)*8] = acc[rr][cc];
    }
  }
}

// ============================================================
// Kernel 5: output projection. out[b][d][v][ij] = Wo[d] . vo[b,v,ij,:] + bo[d]
// ============================================================
__global__ __launch_bounds__(256)
void k_outproj(const float* __restrict__ vo, const float* __restrict__ Wo,
               const float* __restrict__ bo, float* __restrict__ out) {
  const int tid = threadIdx.x;
  const int bid = blockIdx.x;
  const int i = bid % 14;
  const int v = (bid / 14) & 3;
  const int b = bid / 56;

  __shared__ alignas(16) float vos[14][772];   // pad 768->772: bank-conflict break
  const float* src = vo + ((size_t)((b*4 + v)*kSS + i*14))*768;
  for (int idx = tid; idx < 14*768; idx += 256)
    vos[idx / 768][idx % 768] = src[idx];
  __syncthreads();

  for (int oi = tid; oi < 96*14; oi += 256) {
    int d = oi / 14, j = oi % 14;
    const float* wrow = Wo + (size_t)d*768;
    float a = bo[d];
    for (int c = 0; c < 768; c += 4) {
      float4 w = *(const float4*)(wrow + c);
      float4 vv = *(const float4*)(&vos[j][c]);
      a += w.x*vv.x + w.y*vv.y + w.z*vv.z + w.w*vv.w;
    }
    out[((size_t)(b*96 + d)*4 + v)*kSS + i*14 + j] = a;
  }
}

// ============================================================
extern "C" void kernel_launch(void* const* d_in, const int* in_sizes, int n_in,
                              void* d_out, int out_size, void* d_ws, size_t ws_size,
                              hipStream_t stream) {
  const float* x    = (const float*)d_in[0];
  const float* Wq   = (const float*)d_in[1];
  const float* bq   = (const float*)d_in[2];
  const float* Wk   = (const float*)d_in[3];
  const float* bk   = (const float*)d_in[4];
  const float* Wv   = (const float*)d_in[5];
  const float* bv   = (const float*)d_in[6];
  const float* Wo   = (const float*)d_in[7];
  const float* bo   = (const float*)d_in[8];
  const float* rw1  = (const float*)d_in[9];
  const float* rb1  = (const float*)d_in[10];
  const float* rgam = (const float*)d_in[11];
  const float* rbet = (const float*)d_in[12];
  const float* rw2  = (const float*)d_in[13];
  const float* rb2  = (const float*)d_in[14];
  const float* cw1  = (const float*)d_in[15];
  const float* cb1  = (const float*)d_in[16];
  const float* cgam = (const float*)d_in[17];
  const float* cbet = (const float*)d_in[18];
  const float* cw2  = (const float*)d_in[19];
  const float* cb2  = (const float*)d_in[20];
  const float* gemb = (const float*)d_in[21];
  // d_in[22..24] = row_rel, col_rel, g_idx: reconstructed analytically.

  float* ws = (float*)d_ws;
  float* Q    = ws + OFF_Q;
  float* K    = ws + OFF_K;
  float* V    = ws + OFF_V;
  float* Frow = ws + OFF_FR;
  float* Fcol = ws + OFF_FC;
  float* Ps   = ws + OFF_PS;
  float* VO   = ws + OFF_VO;
  float* out  = (float*)d_out;

  k_tables<<<1, 64, 0, stream>>>(rw1, rb1, rgam, rbet, rw2, rb2,
                                 cw1, cb1, cgam, cbet, cw2, cb2, Frow, Fcol);
  k_qkv<<<dim3(112, 3), 256, 0, stream>>>(x, Wq, bq, Wk, bk, Wv, bv, Q, K, V);
  k_attn<<<dim3(224, 4), 256, 0, stream>>>(Q, K, Frow, Fcol, gemb, Ps);
  k_pv<<<256, 256, 0, stream>>>(Ps, V, VO);
  k_outproj<<<112, 256, 0, stream>>>(VO, Wo, bo, out);
}

// Round 5
// 327.239 us; speedup vs baseline: 1.2302x; 1.2302x over previous
//
#include <hip/hip_runtime.h>
#include <hip/hip_bf16.h>

// Problem constants
constexpr int kB   = 2;
constexpr int kH   = 8;
constexpr int kG   = 4;
constexpr int kS   = 14;
constexpr int kSS  = 196;   // S*S
constexpr int kKey = 784;   // G*S*S keys per (b,h)
constexpr int kKeyP = 800;  // keys padded to multiple of 32 for MFMA K-loop
constexpr int kMid = 96;
constexpr int kQR  = 28;    // 4 g * 7 j query rows per attention block
constexpr float kScl = 0.10206207261596577f; // 1/sqrt(96)
constexpr float kK2  = 0.14724663682f;       // kScl / ln(2)  (exp2 domain)
constexpr float kCc  = 11.5415603272f;       // 8 nats / ln(2): constant softmax shift (exact)

typedef __attribute__((ext_vector_type(8))) short bf16x8;
typedef __attribute__((ext_vector_type(4))) float f32x4;

// ---------------- workspace layout (float elements) ----------------
constexpr size_t SZ_QKV = (size_t)kB*kH*kG*kSS*kMid;   // 1,204,224
constexpr size_t OFF_Q  = 0;
constexpr size_t OFF_K  = OFF_Q + SZ_QKV;              // K fp32 CHANNEL-MAJOR: [bh][c][key784]
constexpr size_t OFF_V  = OFF_K + SZ_QKV;              // V bf16 CHANNEL-MAJOR: [bh][c][keyP]
constexpr size_t OFF_FR = OFF_V + SZ_QKV;              // 27*32 row table
constexpr size_t OFF_FC = OFF_FR + 27*32;              // 27*32 col table
constexpr size_t OFF_PS = OFF_FC + 27*32;              // Psum bf16 [bh][v*196+ij][keyP]
constexpr size_t SZ_PS  = (size_t)kB*kH*kG*kSS*kKeyP/2; // 5,017,600 floats (bf16 pairs)
constexpr size_t OFF_VO = OFF_PS + SZ_PS;              // vo fp32: 1,204,224
// total = 9,836,224 floats = 39.3 MB

// ============================================================
// Kernel 1: embed tables. row_rel/col_rel only take values n/13, n in [-13,13],
// so the whole (G,S,S,S,S,32) embed tensors reduce to two 27x32 tables.
// ============================================================
__global__ void k_tables(const float* __restrict__ rw1, const float* __restrict__ rb1,
                         const float* __restrict__ rgam, const float* __restrict__ rbet,
                         const float* __restrict__ rw2, const float* __restrict__ rb2,
                         const float* __restrict__ cw1, const float* __restrict__ cb1,
                         const float* __restrict__ cgam, const float* __restrict__ cbet,
                         const float* __restrict__ cw2, const float* __restrict__ cb2,
                         float* __restrict__ frow, float* __restrict__ fcol) {
  int t = threadIdx.x;
  if (t >= 54) return;
  int which = t / 27;
  int n = t % 27;
  float tv = (float)(n - 13) / 13.0f;
  const float* w1  = which ? cw1  : rw1;
  const float* b1  = which ? cb1  : rb1;
  const float* gam = which ? cgam : rgam;
  const float* bet = which ? cbet : rbet;
  const float* w2  = which ? cw2  : rw2;
  const float* b2  = which ? cb2  : rb2;
  float h[16];
  float mu = 0.f;
#pragma unroll
  for (int d = 0; d < 16; ++d) { h[d] = tv * w1[d] + b1[d]; mu += h[d]; }
  mu *= (1.0f/16.0f);
  float var = 0.f;
#pragma unroll
  for (int d = 0; d < 16; ++d) { float z = h[d] - mu; var += z*z; }
  var *= (1.0f/16.0f);
  float rstd = rsqrtf(var + 1e-5f);
#pragma unroll
  for (int d = 0; d < 16; ++d) {
    float z = (h[d] - mu) * rstd * gam[d] + bet[d];
    h[d] = z / (1.0f + expf(-z));   // silu
  }
  float* outp = (which ? fcol : frow) + n*32;
  for (int c = 0; c < 32; ++c) {
    float o = b2[c];
#pragma unroll
    for (int d = 0; d < 16; ++d) o += h[d] * w2[d*32 + c];
    outp[c] = o;
  }
}

// ============================================================
// Kernel 1b: zero the key-pad [784,800) of the bf16 V buffer.
// ============================================================
__global__ void k_vpad(__hip_bfloat16* __restrict__ Vb) {
  int bh = blockIdx.x;
  for (int idx = threadIdx.x; idx < 96*16; idx += 256) {
    int c = idx >> 4, kp = idx & 15;
    Vb[((size_t)(bh*96 + c))*kKeyP + kKey + kp] = __float2bfloat16(0.f);
  }
}

// ============================================================
// Kernel 2: QKV projection (R3-proven body).
// Q fp32 [b][h][g][ij][c].  K fp32 CHANNEL-MAJOR [bh][c][784].
// V bf16 CHANNEL-MAJOR [bh][c][800] (= MFMA B-operand layout for k_pv).
// d = c*8 + h per the reference reshape(MID, HEADS).
// ============================================================
__global__ __launch_bounds__(256)
void k_qkv(const float* __restrict__ x,
           const float* __restrict__ Wq, const float* __restrict__ bq,
           const float* __restrict__ Wk, const float* __restrict__ bk,
           const float* __restrict__ Wv, const float* __restrict__ bv,
           float* __restrict__ Q, float* __restrict__ K,
           __hip_bfloat16* __restrict__ Vb) {
  const int bid = blockIdx.x;
  const int ten = blockIdx.y;
  const int i = bid % 14;
  const int g = (bid / 14) % 4;
  const int b = bid / 56;
  const float* W    = (ten == 0) ? Wq : (ten == 1) ? Wk : Wv;
  const float* bias = (ten == 0) ? bq : (ten == 1) ? bk : bv;

  __shared__ float xs[96][14];
  for (int idx = threadIdx.x; idx < 96*14; idx += 256) {
    int cin = idx / 14, j = idx % 14;
    xs[cin][j] = x[((size_t)(b*96 + cin)*4 + g)*196 + i*14 + j];
  }
  __syncthreads();

  for (int d = threadIdx.x; d < 768; d += 256) {
    int c = d >> 3, h = d & 7;
    float bvv = bias[d];
    float acc[14];
#pragma unroll
    for (int j = 0; j < 14; ++j) acc[j] = bvv;
    const float* wrow = W + (size_t)d * 96;
    for (int cc = 0; cc < 96; cc += 4) {
      float4 w = *(const float4*)(wrow + cc);
#pragma unroll
      for (int j = 0; j < 14; ++j)
        acc[j] += w.x*xs[cc][j] + w.y*xs[cc+1][j] + w.z*xs[cc+2][j] + w.w*xs[cc+3][j];
    }
    if (ten == 1) {
      float* op = K + ((size_t)((b*8 + h)*96 + c))*784 + g*196 + i*14;
#pragma unroll
      for (int j = 0; j < 14; ++j) op[j] = acc[j];
    } else if (ten == 2) {
      __hip_bfloat16* op = Vb + ((size_t)((b*8 + h)*96 + c))*kKeyP + g*196 + i*14;
#pragma unroll
      for (int j = 0; j < 14; ++j) op[j] = __float2bfloat16(acc[j]);
    } else {
      float* op = Q + ((size_t)((b*8 + h)*4 + g)*196 + i*14)*96 + c;
#pragma unroll
      for (int j = 0; j < 14; ++j) op[(size_t)j*96] = acc[j];
    }
  }
}

// ============================================================
// Kernel 3: fused content + bias + softmax (R3-proven structure; only the
// Psum store changed to bf16 rows of stride 800 + pad zeroing).
// Block = (b,h,i,jhalf): 28 query rows (4 g x 7 j) vs 784 keys.
// ============================================================
__global__ __launch_bounds__(256, 2)
void k_attn(const float* __restrict__ Q, const float* __restrict__ Kt,
            const float* __restrict__ frow_g, const float* __restrict__ fcol_g,
            const float* __restrict__ gemb_g, __hip_bfloat16* __restrict__ Pb) {
  const int tid = threadIdx.x;
  const int bid = blockIdx.x;
  const int jhalf = bid & 1;
  const int t2 = bid >> 1;
  const int qi = t2 % 14;
  const int hh = (t2 / 14) % 8;
  const int bb = t2 / 112;
  const int bh = bb*8 + hh;

  __shared__ alignas(16) float qs[kQR][96];
  __shared__ alignas(16) float frowS[27*32];
  __shared__ alignas(16) float fcolS[27*32];
  __shared__ alignas(16) float gembS[128];
  __shared__ float Arr2[kQR][27];             // row bias dot, pre-scaled by kK2
  __shared__ float Acl2[kQR][27];             // col bias dot, pre-scaled by kK2
  __shared__ float AgE[kQR][4];               // exp2(group bias * kK2)
  __shared__ float AgErot[kQR][4];            // per-v rotated AgE
  __shared__ float redw[kQR][4];
  __shared__ float DinvS[kQR];
  __shared__ __hip_bfloat16 contl[kQR][kKey]; // E values: [q][m*196 + kl]

  // ---- stage queries + tables (tables pre-scaled into exp2 domain)
  for (int idx = tid; idx < kQR*96; idx += 256) {
    int q = idx / 96, c = idx - q*96;
    int g = q / 7, jq = q - g*7;
    qs[q][c] = Q[((size_t)((bh*4 + g)*kSS + qi*14 + jhalf*7 + jq))*96 + c];
  }
  for (int idx = tid; idx < 864; idx += 256) frowS[idx] = frow_g[idx] * kK2;
  for (int idx = tid; idx < 864; idx += 256) fcolS[idx] = fcol_g[idx] * kK2;
  if (tid < 128) gembS[tid] = gemb_g[tid] * kK2;
  __syncthreads();

  // ---- per-query bias tables (exp2 domain)
  for (int t = tid; t < kQR*58; t += 256) {
    int q = t / 58, s = t - q*58;
    float acc = 0.f;
    if (s < 27) {
#pragma unroll
      for (int c = 0; c < 32; ++c) acc += qs[q][c] * frowS[s*32 + c];
      Arr2[q][s] = acc;
    } else if (s < 54) {
      int n = s - 27;
#pragma unroll
      for (int c = 0; c < 32; ++c) acc += qs[q][32+c] * fcolS[n*32 + c];
      Acl2[q][n] = acc;
    } else {
      int p = s - 54;
#pragma unroll
      for (int c = 0; c < 32; ++c) acc += qs[q][64+c] * gembS[p*32 + c];
      AgE[q][p] = exp2f(acc);
    }
  }
  __syncthreads();

  // ---- content GEMM: thread owns key-col kl=tid (<196), all 4 m in registers.
  if (tid < 196) {
    const float* kb = Kt + (size_t)bh*96*784 + tid;
    for (int h2 = 0; h2 < 2; ++h2) {
      float acc[14][4];
#pragma unroll
      for (int q = 0; q < 14; ++q)
#pragma unroll
        for (int m = 0; m < 4; ++m) acc[q][m] = 0.f;
      for (int cc = 0; cc < 96; cc += 4) {
        float kf[4][4];
#pragma unroll
        for (int c = 0; c < 4; ++c)
#pragma unroll
          for (int m = 0; m < 4; ++m)
            kf[c][m] = kb[(size_t)(cc + c)*784 + m*196];
#pragma unroll
        for (int q = 0; q < 14; ++q) {
          float4 qv = *(const float4*)(&qs[h2*14 + q][cc]);
#pragma unroll
          for (int m = 0; m < 4; ++m)
            acc[q][m] += qv.x*kf[0][m] + qv.y*kf[1][m] + qv.z*kf[2][m] + qv.w*kf[3][m];
        }
      }
      // E = exp2(content*kK2 - Cc), scalar bf16 stores
#pragma unroll
      for (int q = 0; q < 14; ++q)
#pragma unroll
        for (int m = 0; m < 4; ++m)
          contl[h2*14 + q][m*196 + tid] = __float2bfloat16(exp2f(acc[q][m]*kK2 - kCc));
    }
  }
  __syncthreads();

  const int kk = (tid < 196) ? (tid / 14) : 0;
  const int ll = (tid < 196) ? (tid % 14) : 0;
  const int da = kk - qi;

  for (int v = 0; v < 4; ++v) {
    int s1a, s1b, s2a, s2b;
    if (v == 0)      { s1a = 1;  s1b = 0;  s2a = 0;  s2b = 1;  }
    else if (v == 1) { s1a = 0;  s1b = -1; s2a = 1;  s2b = 0;  }
    else if (v == 2) { s1a = -1; s1b = 0;  s2a = 0;  s2b = -1; }
    else             { s1a = 0;  s1b = 1;  s2a = -1; s2b = 0;  }

    if (tid < 112) {
      int q = tid >> 2, m = tid & 3, gq = q / 7;
      AgErot[q][m] = AgE[q][(m - gq + v + 8) & 3];
    }
    __syncthreads();

    // ---- pass B: denominators. Per-thread partial per q, shuffle-reduce.
    float arvE[kQR];
    float prt[kQR];
    if (tid < 196) {
#pragma unroll
      for (int gq = 0; gq < 4; ++gq) {
#pragma unroll
        for (int jq = 0; jq < 7; ++jq) {
          const int q = gq*7 + jq;
          const int db = ll - (jhalf*7 + jq);
          const int ai = s1a*da + s1b*db, ci = s2a*da + s2b*db;
          arvE[q] = exp2f(Arr2[q][13 + ai] + Acl2[q][13 + ci]);
          float e0 = __bfloat162float(contl[q][0*196 + tid]);
          float e1 = __bfloat162float(contl[q][1*196 + tid]);
          float e2 = __bfloat162float(contl[q][2*196 + tid]);
          float e3 = __bfloat162float(contl[q][3*196 + tid]);
          prt[q] = (e0*AgErot[q][0] + e1*AgErot[q][1] +
                    e2*AgErot[q][2] + e3*AgErot[q][3]) * arvE[q];
        }
      }
    } else {
#pragma unroll
      for (int q = 0; q < kQR; ++q) { prt[q] = 0.f; arvE[q] = 0.f; }
    }
#pragma unroll
    for (int q = 0; q < kQR; ++q) {
      float s = prt[q];
#pragma unroll
      for (int off = 1; off < 64; off <<= 1) s += __shfl_xor(s, off, 64);
      if ((tid & 63) == 0) redw[q][tid >> 6] = s;
    }
    __syncthreads();
    if (tid < kQR)
      DinvS[tid] = 1.0f / (redw[tid][0] + redw[tid][1] + redw[tid][2] + redw[tid][3]);
    __syncthreads();

    // ---- pass C: normalized probs (no transcendentals), summed over g.
    // Stored bf16, row stride 800 (MFMA A-operand layout for k_pv).
    if (tid < 196) {
      __hip_bfloat16* pbase =
          Pb + ((size_t)((bh*4 + v)*kSS + qi*14 + jhalf*7))*kKeyP + tid;
#pragma unroll
      for (int jq = 0; jq < 7; ++jq) {
        float am[4] = {0.f, 0.f, 0.f, 0.f};
#pragma unroll
        for (int gq = 0; gq < 4; ++gq) {
          const int q = gq*7 + jq;
          const float fq = arvE[q] * DinvS[q];
          float e0 = __bfloat162float(contl[q][0*196 + tid]);
          float e1 = __bfloat162float(contl[q][1*196 + tid]);
          float e2 = __bfloat162float(contl[q][2*196 + tid]);
          float e3 = __bfloat162float(contl[q][3*196 + tid]);
          am[0] += e0 * (AgErot[q][0] * fq);
          am[1] += e1 * (AgErot[q][1] * fq);
          am[2] += e2 * (AgErot[q][2] * fq);
          am[3] += e3 * (AgErot[q][3] * fq);
        }
        __hip_bfloat16* pp = pbase + (size_t)jq*kKeyP;
#pragma unroll
        for (int m = 0; m < 4; ++m) pp[m*196] = __float2bfloat16(am[m]);
      }
    }
    // zero the key-pad [784,800) of this block's 7 rows for this v
    if (tid < 112) {
      int jq = tid >> 4, kp = tid & 15;
      Pb[((size_t)((bh*4 + v)*kSS + qi*14 + jhalf*7 + jq))*kKeyP + kKey + kp] =
          __float2bfloat16(0.f);
    }
    __syncthreads();   // protects AgErot for next v
  }
}

// ============================================================
// Kernel 4: PV GEMM via bf16 MFMA, zero LDS, zero barriers.
// Block = (bh, M-tile of 16 rows of (v,ij)); D[16x96] = P[16x800] * V[800x96].
// A,B fragments loaded straight from global (L2-hot; rows streamed linearly).
// 784 blocks x 128 thr (2 waves x 3 N-tiles).
// ============================================================
__global__ __launch_bounds__(128)
void k_pv(const __hip_bfloat16* __restrict__ Pb,
          const __hip_bfloat16* __restrict__ Vb, float* __restrict__ vo) {
  const int tid  = threadIdx.x;
  const int lane = tid & 63;
  const int wave = tid >> 6;
  const int bh = blockIdx.x / 49;
  const int mt = blockIdx.x % 49;
  const int mrow = lane & 15;     // A row within M-tile / B,N col within N-tile
  const int quad = lane >> 4;

  const short* Ap = (const short*)Pb +
      ((size_t)(bh*kKey + mt*16 + mrow))*kKeyP + quad*8;
  const short* Bp = (const short*)Vb + ((size_t)bh*96)*kKeyP + quad*8;

  f32x4 acc0 = {0.f,0.f,0.f,0.f};
  f32x4 acc1 = {0.f,0.f,0.f,0.f};
  f32x4 acc2 = {0.f,0.f,0.f,0.f};

  const int n0 = (wave*3 + 0)*16 + mrow;
  const int n1 = (wave*3 + 1)*16 + mrow;
  const int n2 = (wave*3 + 2)*16 + mrow;

  for (int ks = 0; ks < kKeyP/32; ++ks) {
    bf16x8 a  = *(const bf16x8*)(Ap + ks*32);
    bf16x8 b0 = *(const bf16x8*)(Bp + (size_t)n0*kKeyP + ks*32);
    bf16x8 b1 = *(const bf16x8*)(Bp + (size_t)n1*kKeyP + ks*32);
    bf16x8 b2 = *(const bf16x8*)(Bp + (size_t)n2*kKeyP + ks*32);
    acc0 = __builtin_amdgcn_mfma_f32_16x16x32_bf16(a, b0, acc0, 0, 0, 0);
    acc1 = __builtin_amdgcn_mfma_f32_16x16x32_bf16(a, b1, acc1, 0, 0, 0);
    acc2 = __builtin_amdgcn_mfma_f32_16x16x32_bf16(a, b2, acc2, 0, 0, 0);
  }

  const int b_ = bh >> 3, h_ = bh & 7;
  // C/D layout: col = lane&15, row = quad*4 + reg  [m89-verified]
#pragma unroll
  for (int r = 0; r < 4; ++r) {
    int m  = mt*16 + quad*4 + r;
    int v  = m / kSS, ij = m % kSS;
    float* op = vo + ((size_t)((b_*4 + v)*kSS + ij))*768 + h_;
    op[(size_t)(n0)*8] = acc0[r];
    op[(size_t)(n1)*8] = acc1[r];
    op[(size_t)(n2)*8] = acc2[r];
  }
}

// ============================================================
// Kernel 5: output projection. out[b][d][v][ij] = Wo[d] . vo[b,v,ij,:] + bo[d]
// ============================================================
__global__ __launch_bounds__(256)
void k_outproj(const float* __restrict__ vo, const float* __restrict__ Wo,
               const float* __restrict__ bo, float* __restrict__ out) {
  const int tid = threadIdx.x;
  const int bid = blockIdx.x;
  const int i = bid % 14;
  const int v = (bid / 14) & 3;
  const int b = bid / 56;

  __shared__ alignas(16) float vos[14][772];   // pad 768->772: bank-conflict break
  const float* src = vo + ((size_t)((b*4 + v)*kSS + i*14))*768;
  for (int idx = tid; idx < 14*768; idx += 256)
    vos[idx / 768][idx % 768] = src[idx];
  __syncthreads();

  for (int oi = tid; oi < 96*14; oi += 256) {
    int d = oi / 14, j = oi % 14;
    const float* wrow = Wo + (size_t)d*768;
    float a = bo[d];
    for (int c = 0; c < 768; c += 4) {
      float4 w = *(const float4*)(wrow + c);
      float4 vv = *(const float4*)(&vos[j][c]);
      a += w.x*vv.x + w.y*vv.y + w.z*vv.z + w.w*vv.w;
    }
    out[((size_t)(b*96 + d)*4 + v)*kSS + i*14 + j] = a;
  }
}

// ============================================================
extern "C" void kernel_launch(void* const* d_in, const int* in_sizes, int n_in,
                              void* d_out, int out_size, void* d_ws, size_t ws_size,
                              hipStream_t stream) {
  const float* x    = (const float*)d_in[0];
  const float* Wq   = (const float*)d_in[1];
  const float* bq   = (const float*)d_in[2];
  const float* Wk   = (const float*)d_in[3];
  const float* bk   = (const float*)d_in[4];
  const float* Wv   = (const float*)d_in[5];
  const float* bv   = (const float*)d_in[6];
  const float* Wo   = (const float*)d_in[7];
  const float* bo   = (const float*)d_in[8];
  const float* rw1  = (const float*)d_in[9];
  const float* rb1  = (const float*)d_in[10];
  const float* rgam = (const float*)d_in[11];
  const float* rbet = (const float*)d_in[12];
  const float* rw2  = (const float*)d_in[13];
  const float* rb2  = (const float*)d_in[14];
  const float* cw1  = (const float*)d_in[15];
  const float* cb1  = (const float*)d_in[16];
  const float* cgam = (const float*)d_in[17];
  const float* cbet = (const float*)d_in[18];
  const float* cw2  = (const float*)d_in[19];
  const float* cb2  = (const float*)d_in[20];
  const float* gemb = (const float*)d_in[21];
  // d_in[22..24] = row_rel, col_rel, g_idx: reconstructed analytically.

  float* ws = (float*)d_ws;
  float* Q    = ws + OFF_Q;
  float* K    = ws + OFF_K;
  __hip_bfloat16* Vb = (__hip_bfloat16*)(ws + OFF_V);
  float* Frow = ws + OFF_FR;
  float* Fcol = ws + OFF_FC;
  __hip_bfloat16* Pb = (__hip_bfloat16*)(ws + OFF_PS);
  float* VO   = ws + OFF_VO;
  float* out  = (float*)d_out;

  k_tables<<<1, 64, 0, stream>>>(rw1, rb1, rgam, rbet, rw2, rb2,
                                 cw1, cb1, cgam, cbet, cw2, cb2, Frow, Fcol);
  k_vpad<<<16, 256, 0, stream>>>(Vb);
  k_qkv<<<dim3(112, 3), 256, 0, stream>>>(x, Wq, bq, Wk, bk, Wv, bv, Q, K, Vb);
  k_attn<<<448, 256, 0, stream>>>(Q, K, Frow, Fcol, gemb, Pb);
  k_pv<<<784, 128, 0, stream>>>(Pb, Vb, VO);
  k_outproj<<<112, 256, 0, stream>>>(VO, Wo, bo, out);
}

// Round 6
// 299.747 us; speedup vs baseline: 1.3431x; 1.0917x over previous
//
#include <hip/hip_runtime.h>
#include <hip/hip_bf16.h>

// Problem constants
constexpr int kB   = 2;
constexpr int kH   = 8;
constexpr int kG   = 4;
constexpr int kS   = 14;
constexpr int kSS  = 196;   // S*S
constexpr int kKey = 784;   // G*S*S keys per (b,h)
constexpr int kKeyP = 800;  // keys padded to multiple of 32 for MFMA K-loop
constexpr int kMid = 96;
constexpr int kQR  = 28;    // 4 g * 7 j query rows per attention block
constexpr float kScl = 0.10206207261596577f; // 1/sqrt(96)
constexpr float kK2  = 0.14724663682f;       // kScl / ln(2)  (exp2 domain)
constexpr float kCc  = 11.5415603272f;       // 8 nats / ln(2): constant softmax shift (exact)

typedef __attribute__((ext_vector_type(8))) short bf16x8;
typedef __attribute__((ext_vector_type(4))) float f32x4;

// ---------------- workspace layout (float elements) ----------------
constexpr size_t SZ_QKV = (size_t)kB*kH*kG*kSS*kMid;   // 1,204,224
constexpr size_t OFF_Q  = 0;
constexpr size_t OFF_K  = OFF_Q + SZ_QKV;              // K fp32 CHANNEL-MAJOR: [bh][c][key784]
constexpr size_t OFF_V  = OFF_K + SZ_QKV;              // V bf16 CHANNEL-MAJOR: [bh][c][keyP]
constexpr size_t OFF_FR = OFF_V + SZ_QKV;              // 27*32 row table
constexpr size_t OFF_FC = OFF_FR + 27*32;              // 27*32 col table
constexpr size_t OFF_PS = OFF_FC + 27*32;              // Psum bf16 [bh][v*196+ij][keyP]
constexpr size_t SZ_PS  = (size_t)kB*kH*kG*kSS*kKeyP/2; // 5,017,600 floats (bf16 pairs)
constexpr size_t OFF_VO = OFF_PS + SZ_PS;              // vo fp32: 1,204,224

// ============================================================
// Kernel 1: setup. Blocks 0..15: zero V key-pad. Block 16: embed tables
// (row_rel/col_rel only take values n/13, n in [-13,13], so the whole
// (G,S,S,S,S,32) embed tensors reduce to two 27x32 tables).
// ============================================================
__global__ void k_setup(const float* __restrict__ rw1, const float* __restrict__ rb1,
                        const float* __restrict__ rgam, const float* __restrict__ rbet,
                        const float* __restrict__ rw2, const float* __restrict__ rb2,
                        const float* __restrict__ cw1, const float* __restrict__ cb1,
                        const float* __restrict__ cgam, const float* __restrict__ cbet,
                        const float* __restrict__ cw2, const float* __restrict__ cb2,
                        float* __restrict__ frow, float* __restrict__ fcol,
                        __hip_bfloat16* __restrict__ Vb) {
  if (blockIdx.x < 16) {
    int bh = blockIdx.x;
    for (int idx = threadIdx.x; idx < 96*16; idx += 256) {
      int c = idx >> 4, kp = idx & 15;
      Vb[((size_t)(bh*96 + c))*kKeyP + kKey + kp] = __float2bfloat16(0.f);
    }
    return;
  }
  int t = threadIdx.x;
  if (t >= 54) return;
  int which = t / 27;
  int n = t % 27;
  float tv = (float)(n - 13) / 13.0f;
  const float* w1  = which ? cw1  : rw1;
  const float* b1  = which ? cb1  : rb1;
  const float* gam = which ? cgam : rgam;
  const float* bet = which ? cbet : rbet;
  const float* w2  = which ? cw2  : rw2;
  const float* b2  = which ? cb2  : rb2;
  float h[16];
  float mu = 0.f;
#pragma unroll
  for (int d = 0; d < 16; ++d) { h[d] = tv * w1[d] + b1[d]; mu += h[d]; }
  mu *= (1.0f/16.0f);
  float var = 0.f;
#pragma unroll
  for (int d = 0; d < 16; ++d) { float z = h[d] - mu; var += z*z; }
  var *= (1.0f/16.0f);
  float rstd = rsqrtf(var + 1e-5f);
#pragma unroll
  for (int d = 0; d < 16; ++d) {
    float z = (h[d] - mu) * rstd * gam[d] + bet[d];
    h[d] = z / (1.0f + expf(-z));   // silu
  }
  float* outp = (which ? fcol : frow) + n*32;
  for (int c = 0; c < 32; ++c) {
    float o = b2[c];
#pragma unroll
    for (int d = 0; d < 16; ++d) o += h[d] * w2[d*32 + c];
    outp[c] = o;
  }
}

// ============================================================
// Kernel 2: QKV projection. xs staged TRANSPOSED ([j][cin], padded row 100)
// so the inner loop reads one float4 per (j,cc) instead of 4 scalars.
// All lanes read the same xs address -> LDS broadcast, conflict-free.
// Q fp32 [b][h][g][ij][c].  K fp32 CHANNEL-MAJOR [bh][c][784].
// V bf16 CHANNEL-MAJOR [bh][c][800] (= MFMA B-operand layout for k_pv).
// d = c*8 + h per the reference reshape(MID, HEADS).
// ============================================================
__global__ __launch_bounds__(256)
void k_qkv(const float* __restrict__ x,
           const float* __restrict__ Wq, const float* __restrict__ bq,
           const float* __restrict__ Wk, const float* __restrict__ bk,
           const float* __restrict__ Wv, const float* __restrict__ bv,
           float* __restrict__ Q, float* __restrict__ K,
           __hip_bfloat16* __restrict__ Vb) {
  const int bid = blockIdx.x;
  const int ten = blockIdx.y;
  const int i = bid % 14;
  const int g = (bid / 14) % 4;
  const int b = bid / 56;
  const float* W    = (ten == 0) ? Wq : (ten == 1) ? Wk : Wv;
  const float* bias = (ten == 0) ? bq : (ten == 1) ? bk : bv;

  __shared__ alignas(16) float xs[14][100];   // row stride 400 B (16B-aligned)
  for (int idx = threadIdx.x; idx < 96*14; idx += 256) {
    int cin = idx / 14, j = idx % 14;
    xs[j][cin] = x[((size_t)(b*96 + cin)*4 + g)*196 + i*14 + j];
  }
  __syncthreads();

  for (int d = threadIdx.x; d < 768; d += 256) {
    int c = d >> 3, h = d & 7;
    float bvv = bias[d];
    float acc[14];
#pragma unroll
    for (int j = 0; j < 14; ++j) acc[j] = bvv;
    const float* wrow = W + (size_t)d * 96;
    for (int cc = 0; cc < 96; cc += 4) {
      float4 w = *(const float4*)(wrow + cc);
#pragma unroll
      for (int j = 0; j < 14; ++j) {
        float4 xv = *(const float4*)(&xs[j][cc]);
        acc[j] += w.x*xv.x + w.y*xv.y + w.z*xv.z + w.w*xv.w;
      }
    }
    if (ten == 1) {
      float* op = K + ((size_t)((b*8 + h)*96 + c))*784 + g*196 + i*14;
#pragma unroll
      for (int j = 0; j < 14; ++j) op[j] = acc[j];
    } else if (ten == 2) {
      __hip_bfloat16* op = Vb + ((size_t)((b*8 + h)*96 + c))*kKeyP + g*196 + i*14;
#pragma unroll
      for (int j = 0; j < 14; ++j) op[j] = __float2bfloat16(acc[j]);
    } else {
      float* op = Q + ((size_t)((b*8 + h)*4 + g)*196 + i*14)*96 + c;
#pragma unroll
      for (int j = 0; j < 14; ++j) op[(size_t)j*96] = acc[j];
    }
  }
}

// ============================================================
// Kernel 3: fused content + bias + softmax (R5 structure; E now lives in
// PACKED-BF16 REGISTERS instead of the contl LDS array -- the thread that
// computes E(q,m,kl=tid) is the same one that consumes it, so the LDS hop
// was pure register-pressure relief. LDS 69.6 -> 25.7 KB; ~1000 LDS
// instructions/thread removed; numerics bit-identical).
// Block = (b,h,i,jhalf): 28 query rows (4 g x 7 j) vs 784 keys.
// ============================================================
__global__ __launch_bounds__(256, 2)
void k_attn(const float* __restrict__ Q, const float* __restrict__ Kt,
            const float* __restrict__ frow_g, const float* __restrict__ fcol_g,
            const float* __restrict__ gemb_g, __hip_bfloat16* __restrict__ Pb) {
  const int tid = threadIdx.x;
  const int bid = blockIdx.x;
  const int jhalf = bid & 1;
  const int t2 = bid >> 1;
  const int qi = t2 % 14;
  const int hh = (t2 / 14) % 8;
  const int bb = t2 / 112;
  const int bh = bb*8 + hh;

  __shared__ alignas(16) float qs[kQR][96];
  __shared__ alignas(16) float frowS[27*32];
  __shared__ alignas(16) float fcolS[27*32];
  __shared__ alignas(16) float gembS[128];
  __shared__ float Arr2[kQR][27];             // row bias dot, pre-scaled by kK2
  __shared__ float Acl2[kQR][27];             // col bias dot, pre-scaled by kK2
  __shared__ float AgE[kQR][4];               // exp2(group bias * kK2)
  __shared__ float AgErot[kQR][4];            // per-v rotated AgE
  __shared__ float redw[kQR][4];
  __shared__ float DinvS[kQR];

  // ---- stage queries + tables (tables pre-scaled into exp2 domain)
  for (int idx = tid; idx < kQR*96; idx += 256) {
    int q = idx / 96, c = idx - q*96;
    int g = q / 7, jq = q - g*7;
    qs[q][c] = Q[((size_t)((bh*4 + g)*kSS + qi*14 + jhalf*7 + jq))*96 + c];
  }
  for (int idx = tid; idx < 864; idx += 256) frowS[idx] = frow_g[idx] * kK2;
  for (int idx = tid; idx < 864; idx += 256) fcolS[idx] = fcol_g[idx] * kK2;
  if (tid < 128) gembS[tid] = gemb_g[tid] * kK2;
  __syncthreads();

  // ---- per-query bias tables (exp2 domain)
  for (int t = tid; t < kQR*58; t += 256) {
    int q = t / 58, s = t - q*58;
    float acc = 0.f;
    if (s < 27) {
#pragma unroll
      for (int c = 0; c < 32; ++c) acc += qs[q][c] * frowS[s*32 + c];
      Arr2[q][s] = acc;
    } else if (s < 54) {
      int n = s - 27;
#pragma unroll
      for (int c = 0; c < 32; ++c) acc += qs[q][32+c] * fcolS[n*32 + c];
      Acl2[q][n] = acc;
    } else {
      int p = s - 54;
#pragma unroll
      for (int c = 0; c < 32; ++c) acc += qs[q][64+c] * gembS[p*32 + c];
      AgE[q][p] = exp2f(acc);
    }
  }
  __syncthreads();

  // ---- content GEMM: thread owns key-col kl=tid (<196), all 4 m in registers.
  // E = exp2(content*kK2 - Cc) packed bf16 into Ep[q] = {m1m0, m3m2}.
  unsigned int Ep[kQR][2];
#pragma unroll
  for (int q = 0; q < kQR; ++q) { Ep[q][0] = 0u; Ep[q][1] = 0u; }
  if (tid < 196) {
    const float* kb = Kt + (size_t)bh*96*784 + tid;
#pragma unroll
    for (int h2 = 0; h2 < 2; ++h2) {
      float acc[14][4];
#pragma unroll
      for (int q = 0; q < 14; ++q)
#pragma unroll
        for (int m = 0; m < 4; ++m) acc[q][m] = 0.f;
      for (int cc = 0; cc < 96; cc += 4) {
        float kf[4][4];
#pragma unroll
        for (int c = 0; c < 4; ++c)
#pragma unroll
          for (int m = 0; m < 4; ++m)
            kf[c][m] = kb[(size_t)(cc + c)*784 + m*196];
#pragma unroll
        for (int q = 0; q < 14; ++q) {
          float4 qv = *(const float4*)(&qs[h2*14 + q][cc]);
#pragma unroll
          for (int m = 0; m < 4; ++m)
            acc[q][m] += qv.x*kf[0][m] + qv.y*kf[1][m] + qv.z*kf[2][m] + qv.w*kf[3][m];
        }
      }
#pragma unroll
      for (int q = 0; q < 14; ++q) {
        unsigned short us[4];
#pragma unroll
        for (int m = 0; m < 4; ++m) {
          __hip_bfloat16 hv = __float2bfloat16(exp2f(acc[q][m]*kK2 - kCc));
          us[m] = *reinterpret_cast<unsigned short*>(&hv);
        }
        Ep[h2*14 + q][0] = ((unsigned)us[1] << 16) | us[0];
        Ep[h2*14 + q][1] = ((unsigned)us[3] << 16) | us[2];
      }
    }
  }
  // no barrier needed here: E is register-resident now

  const int kk = (tid < 196) ? (tid / 14) : 0;
  const int ll = (tid < 196) ? (tid % 14) : 0;
  const int da = kk - qi;

  for (int v = 0; v < 4; ++v) {
    int s1a, s1b, s2a, s2b;
    if (v == 0)      { s1a = 1;  s1b = 0;  s2a = 0;  s2b = 1;  }
    else if (v == 1) { s1a = 0;  s1b = -1; s2a = 1;  s2b = 0;  }
    else if (v == 2) { s1a = -1; s1b = 0;  s2a = 0;  s2b = -1; }
    else             { s1a = 0;  s1b = 1;  s2a = -1; s2b = 0;  }

    if (tid < 112) {
      int q = tid >> 2, m = tid & 3, gq = q / 7;
      AgErot[q][m] = AgE[q][(m - gq + v + 8) & 3];
    }
    __syncthreads();

    // ---- pass B: denominators. Per-thread partial per q, shuffle-reduce.
    float arvE[kQR];
    float prt[kQR];
    if (tid < 196) {
#pragma unroll
      for (int gq = 0; gq < 4; ++gq) {
#pragma unroll
        for (int jq = 0; jq < 7; ++jq) {
          const int q = gq*7 + jq;
          const int db = ll - (jhalf*7 + jq);
          const int ai = s1a*da + s1b*db, ci = s2a*da + s2b*db;
          arvE[q] = exp2f(Arr2[q][13 + ai] + Acl2[q][13 + ci]);
          float e0 = __uint_as_float(Ep[q][0] << 16);
          float e1 = __uint_as_float(Ep[q][0] & 0xffff0000u);
          float e2 = __uint_as_float(Ep[q][1] << 16);
          float e3 = __uint_as_float(Ep[q][1] & 0xffff0000u);
          prt[q] = (e0*AgErot[q][0] + e1*AgErot[q][1] +
                    e2*AgErot[q][2] + e3*AgErot[q][3]) * arvE[q];
        }
      }
    } else {
#pragma unroll
      for (int q = 0; q < kQR; ++q) { prt[q] = 0.f; arvE[q] = 0.f; }
    }
#pragma unroll
    for (int q = 0; q < kQR; ++q) {
      float s = prt[q];
#pragma unroll
      for (int off = 1; off < 64; off <<= 1) s += __shfl_xor(s, off, 64);
      if ((tid & 63) == 0) redw[q][tid >> 6] = s;
    }
    __syncthreads();
    if (tid < kQR)
      DinvS[tid] = 1.0f / (redw[tid][0] + redw[tid][1] + redw[tid][2] + redw[tid][3]);
    __syncthreads();

    // ---- pass C: normalized probs (no transcendentals), summed over g.
    // Stored bf16, row stride 800 (MFMA A-operand layout for k_pv).
    if (tid < 196) {
      __hip_bfloat16* pbase =
          Pb + ((size_t)((bh*4 + v)*kSS + qi*14 + jhalf*7))*kKeyP + tid;
#pragma unroll
      for (int jq = 0; jq < 7; ++jq) {
        float am[4] = {0.f, 0.f, 0.f, 0.f};
#pragma unroll
        for (int gq = 0; gq < 4; ++gq) {
          const int q = gq*7 + jq;
          const float fq = arvE[q] * DinvS[q];
          float e0 = __uint_as_float(Ep[q][0] << 16);
          float e1 = __uint_as_float(Ep[q][0] & 0xffff0000u);
          float e2 = __uint_as_float(Ep[q][1] << 16);
          float e3 = __uint_as_float(Ep[q][1] & 0xffff0000u);
          am[0] += e0 * (AgErot[q][0] * fq);
          am[1] += e1 * (AgErot[q][1] * fq);
          am[2] += e2 * (AgErot[q][2] * fq);
          am[3] += e3 * (AgErot[q][3] * fq);
        }
        __hip_bfloat16* pp = pbase + (size_t)jq*kKeyP;
#pragma unroll
        for (int m = 0; m < 4; ++m) pp[m*196] = __float2bfloat16(am[m]);
      }
    }
    // zero the key-pad [784,800) of this block's 7 rows for this v
    if (tid < 112) {
      int jq = tid >> 4, kp = tid & 15;
      Pb[((size_t)((bh*4 + v)*kSS + qi*14 + jhalf*7 + jq))*kKeyP + kKey + kp] =
          __float2bfloat16(0.f);
    }
    __syncthreads();   // protects AgErot for next v
  }
}

// ============================================================
// Kernel 4: PV GEMM via bf16 MFMA, zero LDS, zero barriers (R5-proven).
// Block = (bh, M-tile of 16 rows of (v,ij)); D[16x96] = P[16x800] * V[800x96].
// ============================================================
__global__ __launch_bounds__(128)
void k_pv(const __hip_bfloat16* __restrict__ Pb,
          const __hip_bfloat16* __restrict__ Vb, float* __restrict__ vo) {
  const int tid  = threadIdx.x;
  const int lane = tid & 63;
  const int wave = tid >> 6;
  const int bh = blockIdx.x / 49;
  const int mt = blockIdx.x % 49;
  const int mrow = lane & 15;
  const int quad = lane >> 4;

  const short* Ap = (const short*)Pb +
      ((size_t)(bh*kKey + mt*16 + mrow))*kKeyP + quad*8;
  const short* Bp = (const short*)Vb + ((size_t)bh*96)*kKeyP + quad*8;

  f32x4 acc0 = {0.f,0.f,0.f,0.f};
  f32x4 acc1 = {0.f,0.f,0.f,0.f};
  f32x4 acc2 = {0.f,0.f,0.f,0.f};

  const int n0 = (wave*3 + 0)*16 + mrow;
  const int n1 = (wave*3 + 1)*16 + mrow;
  const int n2 = (wave*3 + 2)*16 + mrow;

  for (int ks = 0; ks < kKeyP/32; ++ks) {
    bf16x8 a  = *(const bf16x8*)(Ap + ks*32);
    bf16x8 b0 = *(const bf16x8*)(Bp + (size_t)n0*kKeyP + ks*32);
    bf16x8 b1 = *(const bf16x8*)(Bp + (size_t)n1*kKeyP + ks*32);
    bf16x8 b2 = *(const bf16x8*)(Bp + (size_t)n2*kKeyP + ks*32);
    acc0 = __builtin_amdgcn_mfma_f32_16x16x32_bf16(a, b0, acc0, 0, 0, 0);
    acc1 = __builtin_amdgcn_mfma_f32_16x16x32_bf16(a, b1, acc1, 0, 0, 0);
    acc2 = __builtin_amdgcn_mfma_f32_16x16x32_bf16(a, b2, acc2, 0, 0, 0);
  }

  const int b_ = bh >> 3, h_ = bh & 7;
  // C/D layout: col = lane&15, row = quad*4 + reg  [m89-verified]
#pragma unroll
  for (int r = 0; r < 4; ++r) {
    int m  = mt*16 + quad*4 + r;
    int v  = m / kSS, ij = m % kSS;
    float* op = vo + ((size_t)((b_*4 + v)*kSS + ij))*768 + h_;
    op[(size_t)(n0)*8] = acc0[r];
    op[(size_t)(n1)*8] = acc1[r];
    op[(size_t)(n2)*8] = acc2[r];
  }
}

// ============================================================
// Kernel 5: output projection, d-range split over grid.y (224 blocks).
// out[b][d][v][ij] = Wo[d] . vo[b,v,ij,:] + bo[d]
// ============================================================
__global__ __launch_bounds__(256)
void k_outproj(const float* __restrict__ vo, const float* __restrict__ Wo,
               const float* __restrict__ bo, float* __restrict__ out) {
  const int tid = threadIdx.x;
  const int bid = blockIdx.x;
  const int dhalf = blockIdx.y;
  const int i = bid % 14;
  const int v = (bid / 14) & 3;
  const int b = bid / 56;

  __shared__ alignas(16) float vos[14][772];   // pad 768->772: bank-conflict break
  const float* src = vo + ((size_t)((b*4 + v)*kSS + i*14))*768;
  for (int idx = tid; idx < 14*768; idx += 256)
    vos[idx / 768][idx % 768] = src[idx];
  __syncthreads();

  for (int oi = tid; oi < 48*14; oi += 256) {
    int d = dhalf*48 + oi / 14, j = oi % 14;
    const float* wrow = Wo + (size_t)d*768;
    float a = bo[d];
    for (int c = 0; c < 768; c += 4) {
      float4 w = *(const float4*)(wrow + c);
      float4 vv = *(const float4*)(&vos[j][c]);
      a += w.x*vv.x + w.y*vv.y + w.z*vv.z + w.w*vv.w;
    }
    out[((size_t)(b*96 + d)*4 + v)*kSS + i*14 + j] = a;
  }
}

// ============================================================
extern "C" void kernel_launch(void* const* d_in, const int* in_sizes, int n_in,
                              void* d_out, int out_size, void* d_ws, size_t ws_size,
                              hipStream_t stream) {
  const float* x    = (const float*)d_in[0];
  const float* Wq   = (const float*)d_in[1];
  const float* bq   = (const float*)d_in[2];
  const float* Wk   = (const float*)d_in[3];
  const float* bk   = (const float*)d_in[4];
  const float* Wv   = (const float*)d_in[5];
  const float* bv   = (const float*)d_in[6];
  const float* Wo   = (const float*)d_in[7];
  const float* bo   = (const float*)d_in[8];
  const float* rw1  = (const float*)d_in[9];
  const float* rb1  = (const float*)d_in[10];
  const float* rgam = (const float*)d_in[11];
  const float* rbet = (const float*)d_in[12];
  const float* rw2  = (const float*)d_in[13];
  const float* rb2  = (const float*)d_in[14];
  const float* cw1  = (const float*)d_in[15];
  const float* cb1  = (const float*)d_in[16];
  const float* cgam = (const float*)d_in[17];
  const float* cbet = (const float*)d_in[18];
  const float* cw2  = (const float*)d_in[19];
  const float* cb2  = (const float*)d_in[20];
  const float* gemb = (const float*)d_in[21];
  // d_in[22..24] = row_rel, col_rel, g_idx: reconstructed analytically.

  float* ws = (float*)d_ws;
  float* Q    = ws + OFF_Q;
  float* K    = ws + OFF_K;
  __hip_bfloat16* Vb = (__hip_bfloat16*)(ws + OFF_V);
  float* Frow = ws + OFF_FR;
  float* Fcol = ws + OFF_FC;
  __hip_bfloat16* Pb = (__hip_bfloat16*)(ws + OFF_PS);
  float* VO   = ws + OFF_VO;
  float* out  = (float*)d_out;

  k_setup<<<17, 256, 0, stream>>>(rw1, rb1, rgam, rbet, rw2, rb2,
                                  cw1, cb1, cgam, cbet, cw2, cb2,
                                  Frow, Fcol, Vb);
  k_qkv<<<dim3(112, 3), 256, 0, stream>>>(x, Wq, bq, Wk, bk, Wv, bv, Q, K, Vb);
  k_attn<<<448, 256, 0, stream>>>(Q, K, Frow, Fcol, gemb, Pb);
  k_pv<<<784, 128, 0, stream>>>(Pb, Vb, VO);
  k_outproj<<<dim3(112, 2), 256, 0, stream>>>(VO, Wo, bo, out);
}

// Round 7
// 270.775 us; speedup vs baseline: 1.4868x; 1.1070x over previous
//
#include <hip/hip_runtime.h>
#include <hip/hip_bf16.h>

// Problem constants
constexpr int kB   = 2;
constexpr int kH   = 8;
constexpr int kG   = 4;
constexpr int kS   = 14;
constexpr int kSS  = 196;   // S*S
constexpr int kKey = 784;   // G*S*S keys per (b,h)
constexpr int kKeyP = 800;  // keys padded to multiple of 32 for MFMA K-loop
constexpr int kMid = 96;
constexpr int kQR  = 28;    // 4 g * 7 j query rows per attention block
constexpr int kCL  = 788;   // contl row stride (ushorts; breaks quad bank aliasing)
constexpr float kScl = 0.10206207261596577f; // 1/sqrt(96)
constexpr float kK2  = 0.14724663682f;       // kScl / ln(2)  (exp2 domain)
constexpr float kCc  = 11.5415603272f;       // 8 nats / ln(2): constant softmax shift (exact)

typedef __attribute__((ext_vector_type(8))) short bf16x8;
typedef __attribute__((ext_vector_type(4))) float f32x4;

// ---------------- workspace layout (float elements) ----------------
constexpr size_t SZ_QKb = (size_t)kB*kH*kG*kSS*kMid/2; // 602,112 (bf16 in float units)
constexpr size_t OFF_Qb = 0;                            // Qb bf16 [bh][g*196+ij][96]
constexpr size_t OFF_Kb = OFF_Qb + SZ_QKb;              // Kb bf16 [bh][g*196+ij][96]
constexpr size_t OFF_V  = OFF_Kb + SZ_QKb;              // Vb bf16 CHANNEL-MAJOR [bh][c][800]
constexpr size_t SZ_V   = (size_t)kB*kH*kMid*kKeyP/2;   // 614,400
constexpr size_t OFF_FR = OFF_V + SZ_V;                 // 27*32 row table fp32
constexpr size_t OFF_FC = OFF_FR + 27*32;               // 27*32 col table fp32
constexpr size_t OFF_PS = OFF_FC + 27*32;               // Psum bf16 [bh][v*196+ij][800]
constexpr size_t SZ_PS  = (size_t)kB*kH*kG*kSS*kKeyP/2; // 5,017,600
constexpr size_t OFF_VO = OFF_PS + SZ_PS;               // vo fp32: 1,204,224

// ============================================================
// Kernel 1: setup. Blocks 0..15: zero V key-pad. Block 16: embed tables
// (row_rel/col_rel only take values n/13, n in [-13,13], so the whole
// (G,S,S,S,S,32) embed tensors reduce to two 27x32 tables).
// ============================================================
__global__ void k_setup(const float* __restrict__ rw1, const float* __restrict__ rb1,
                        const float* __restrict__ rgam, const float* __restrict__ rbet,
                        const float* __restrict__ rw2, const float* __restrict__ rb2,
                        const float* __restrict__ cw1, const float* __restrict__ cb1,
                        const float* __restrict__ cgam, const float* __restrict__ cbet,
                        const float* __restrict__ cw2, const float* __restrict__ cb2,
                        float* __restrict__ frow, float* __restrict__ fcol,
                        __hip_bfloat16* __restrict__ Vb) {
  if (blockIdx.x < 16) {
    int bh = blockIdx.x;
    for (int idx = threadIdx.x; idx < 96*16; idx += 256) {
      int c = idx >> 4, kp = idx & 15;
      Vb[((size_t)(bh*96 + c))*kKeyP + kKey + kp] = __float2bfloat16(0.f);
    }
    return;
  }
  int t = threadIdx.x;
  if (t >= 54) return;
  int which = t / 27;
  int n = t % 27;
  float tv = (float)(n - 13) / 13.0f;
  const float* w1  = which ? cw1  : rw1;
  const float* b1  = which ? cb1  : rb1;
  const float* gam = which ? cgam : rgam;
  const float* bet = which ? cbet : rbet;
  const float* w2  = which ? cw2  : rw2;
  const float* b2  = which ? cb2  : rb2;
  float h[16];
  float mu = 0.f;
#pragma unroll
  for (int d = 0; d < 16; ++d) { h[d] = tv * w1[d] + b1[d]; mu += h[d]; }
  mu *= (1.0f/16.0f);
  float var = 0.f;
#pragma unroll
  for (int d = 0; d < 16; ++d) { float z = h[d] - mu; var += z*z; }
  var *= (1.0f/16.0f);
  float rstd = rsqrtf(var + 1e-5f);
#pragma unroll
  for (int d = 0; d < 16; ++d) {
    float z = (h[d] - mu) * rstd * gam[d] + bet[d];
    h[d] = z / (1.0f + expf(-z));   // silu
  }
  float* outp = (which ? fcol : frow) + n*32;
  for (int c = 0; c < 32; ++c) {
    float o = b2[c];
#pragma unroll
    for (int d = 0; d < 16; ++d) o += h[d] * w2[d*32 + c];
    outp[c] = o;
  }
}

// ============================================================
// Kernel 2: QKV projection. Q and K now share the SAME bf16 key-major
// layout [bh][g*196+ij][96] (= MFMA A / B^T operand layout for k_attn).
// V bf16 CHANNEL-MAJOR [bh][c][800] (= MFMA B layout for k_pv).
// d = c*8 + h per the reference reshape(MID, HEADS).
// ============================================================
__global__ __launch_bounds__(256)
void k_qkv(const float* __restrict__ x,
           const float* __restrict__ Wq, const float* __restrict__ bq,
           const float* __restrict__ Wk, const float* __restrict__ bk,
           const float* __restrict__ Wv, const float* __restrict__ bv,
           __hip_bfloat16* __restrict__ Qb, __hip_bfloat16* __restrict__ Kb,
           __hip_bfloat16* __restrict__ Vb) {
  const int bid = blockIdx.x;
  const int ten = blockIdx.y;
  const int i = bid % 14;
  const int g = (bid / 14) % 4;
  const int b = bid / 56;
  const float* W    = (ten == 0) ? Wq : (ten == 1) ? Wk : Wv;
  const float* bias = (ten == 0) ? bq : (ten == 1) ? bk : bv;

  __shared__ alignas(16) float xs[14][100];   // transposed, padded
  for (int idx = threadIdx.x; idx < 96*14; idx += 256) {
    int cin = idx / 14, j = idx % 14;
    xs[j][cin] = x[((size_t)(b*96 + cin)*4 + g)*196 + i*14 + j];
  }
  __syncthreads();

  for (int d = threadIdx.x; d < 768; d += 256) {
    int c = d >> 3, h = d & 7;
    float bvv = bias[d];
    float acc[14];
#pragma unroll
    for (int j = 0; j < 14; ++j) acc[j] = bvv;
    const float* wrow = W + (size_t)d * 96;
    for (int cc = 0; cc < 96; cc += 4) {
      float4 w = *(const float4*)(wrow + cc);
#pragma unroll
      for (int j = 0; j < 14; ++j) {
        float4 xv = *(const float4*)(&xs[j][cc]);
        acc[j] += w.x*xv.x + w.y*xv.y + w.z*xv.z + w.w*xv.w;
      }
    }
    if (ten == 2) {
      __hip_bfloat16* op = Vb + ((size_t)((b*8 + h)*96 + c))*kKeyP + g*196 + i*14;
#pragma unroll
      for (int j = 0; j < 14; ++j) op[j] = __float2bfloat16(acc[j]);
    } else {
      __hip_bfloat16* dst = (ten == 0) ? Qb : Kb;
      __hip_bfloat16* op = dst + ((size_t)((b*8 + h)*4 + g)*196 + i*14)*96 + c;
#pragma unroll
      for (int j = 0; j < 14; ++j) op[(size_t)j*96] = __float2bfloat16(acc[j]);
    }
  }
}

// ============================================================
// Kernel 3: fused content + bias + softmax. QK^T now on MFMA:
// content[32(pad) x 784] = Q[32x96] . K^T, 16x16x32 bf16, 294 MFMAs/block,
// epilogue writes E = exp2(content*kK2 - Cc) bf16 into contl (padded stride).
// Softmax v-loop is the R3/R6-proven code reading contl.
// Block = (b,h,i,jhalf): 28 query rows (4 g x 7 j) vs 784 keys.
// ============================================================
__global__ __launch_bounds__(256, 2)
void k_attn(const __hip_bfloat16* __restrict__ Qb, const __hip_bfloat16* __restrict__ Kb,
            const float* __restrict__ frow_g, const float* __restrict__ fcol_g,
            const float* __restrict__ gemb_g, __hip_bfloat16* __restrict__ Pb) {
  const int tid = threadIdx.x;
  const int bid = blockIdx.x;
  const int jhalf = bid & 1;
  const int t2 = bid >> 1;
  const int qi = t2 % 14;
  const int hh = (t2 / 14) % 8;
  const int bb = t2 / 112;
  const int bh = bb*8 + hh;

  __shared__ alignas(16) float qs[kQR][96];   // fp32 copies for bias dots
  __shared__ alignas(16) float frowS[27*32];
  __shared__ alignas(16) float fcolS[27*32];
  __shared__ alignas(16) float gembS[128];
  __shared__ float Arr2[kQR][27];             // row bias dot, pre-scaled by kK2
  __shared__ float Acl2[kQR][27];             // col bias dot, pre-scaled by kK2
  __shared__ float AgE[kQR][4];               // exp2(group bias * kK2)
  __shared__ float AgErot[kQR][4];            // per-v rotated AgE
  __shared__ float redw[kQR][4];
  __shared__ float DinvS[kQR];
  __shared__ __hip_bfloat16 contl[kQR][kCL];  // E values: [q][kl] (kl = m*196+ij)

  const short* Qs = (const short*)Qb;
  const short* Ks = (const short*)Kb;
  // base row of this block's 28 queries: q -> row (bh*4 + q/7)*196 + qi*14 + jhalf*7 + q%7

  // ---- stage fp32 query copies + tables (tables pre-scaled into exp2 domain)
  for (int idx = tid; idx < kQR*96; idx += 256) {
    int q = idx / 96, c = idx - q*96;
    int g = q / 7, jq = q - g*7;
    qs[q][c] = __bfloat162float(
        Qb[((size_t)((bh*4 + g)*kSS + qi*14 + jhalf*7 + jq))*96 + c]);
  }
  for (int idx = tid; idx < 864; idx += 256) frowS[idx] = frow_g[idx] * kK2;
  for (int idx = tid; idx < 864; idx += 256) fcolS[idx] = fcol_g[idx] * kK2;
  if (tid < 128) gembS[tid] = gemb_g[tid] * kK2;
  __syncthreads();

  // ---- MFMA content GEMM -> contl
  {
    const int lane = tid & 63;
    const int wave = tid >> 6;
    const int col  = lane & 15;
    const int quad = lane >> 4;

    bf16x8 afrag[2][3];
#pragma unroll
    for (int mt = 0; mt < 2; ++mt) {
      int m = mt*16 + col;
      int q = (m < kQR) ? m : 0;                 // pad rows: duplicate q0 (discarded)
      const short* qrow = Qs +
          ((size_t)((bh*4 + q/7)*kSS + qi*14 + jhalf*7 + q%7))*96;
#pragma unroll
      for (int ks = 0; ks < 3; ++ks)
        afrag[mt][ks] = *(const bf16x8*)(qrow + ks*32 + quad*8);
    }

    for (int nt = wave; nt < 49; nt += 4) {
      int kl = nt*16 + col;
      const short* krow = Ks + ((size_t)(bh*kKey + kl))*96;
      bf16x8 b0 = *(const bf16x8*)(krow + 0*32 + quad*8);
      bf16x8 b1 = *(const bf16x8*)(krow + 1*32 + quad*8);
      bf16x8 b2 = *(const bf16x8*)(krow + 2*32 + quad*8);
      f32x4 c0 = {0.f,0.f,0.f,0.f};
      f32x4 c1 = {0.f,0.f,0.f,0.f};
      c0 = __builtin_amdgcn_mfma_f32_16x16x32_bf16(afrag[0][0], b0, c0, 0, 0, 0);
      c0 = __builtin_amdgcn_mfma_f32_16x16x32_bf16(afrag[0][1], b1, c0, 0, 0, 0);
      c0 = __builtin_amdgcn_mfma_f32_16x16x32_bf16(afrag[0][2], b2, c0, 0, 0, 0);
      c1 = __builtin_amdgcn_mfma_f32_16x16x32_bf16(afrag[1][0], b0, c1, 0, 0, 0);
      c1 = __builtin_amdgcn_mfma_f32_16x16x32_bf16(afrag[1][1], b1, c1, 0, 0, 0);
      c1 = __builtin_amdgcn_mfma_f32_16x16x32_bf16(afrag[1][2], b2, c1, 0, 0, 0);
      // C/D layout: col = lane&15 (=n=kl), row = quad*4 + r (=m=q)  [m89]
#pragma unroll
      for (int r = 0; r < 4; ++r) {
        int q0 = quad*4 + r;                     // 0..15, all valid
        contl[q0][kl] = __float2bfloat16(exp2f(c0[r]*kK2 - kCc));
        int q1 = 16 + quad*4 + r;                // 16..31, valid < 28
        if (q1 < kQR)
          contl[q1][kl] = __float2bfloat16(exp2f(c1[r]*kK2 - kCc));
      }
    }
  }

  // ---- per-query bias tables (exp2 domain)
  for (int t = tid; t < kQR*58; t += 256) {
    int q = t / 58, s = t - q*58;
    float acc = 0.f;
    if (s < 27) {
#pragma unroll
      for (int c = 0; c < 32; ++c) acc += qs[q][c] * frowS[s*32 + c];
      Arr2[q][s] = acc;
    } else if (s < 54) {
      int n = s - 27;
#pragma unroll
      for (int c = 0; c < 32; ++c) acc += qs[q][32+c] * fcolS[n*32 + c];
      Acl2[q][n] = acc;
    } else {
      int p = s - 54;
#pragma unroll
      for (int c = 0; c < 32; ++c) acc += qs[q][64+c] * gembS[p*32 + c];
      AgE[q][p] = exp2f(acc);
    }
  }
  __syncthreads();

  const int kk = (tid < 196) ? (tid / 14) : 0;
  const int ll = (tid < 196) ? (tid % 14) : 0;
  const int da = kk - qi;

  for (int v = 0; v < 4; ++v) {
    int s1a, s1b, s2a, s2b;
    if (v == 0)      { s1a = 1;  s1b = 0;  s2a = 0;  s2b = 1;  }
    else if (v == 1) { s1a = 0;  s1b = -1; s2a = 1;  s2b = 0;  }
    else if (v == 2) { s1a = -1; s1b = 0;  s2a = 0;  s2b = -1; }
    else             { s1a = 0;  s1b = 1;  s2a = -1; s2b = 0;  }

    if (tid < 112) {
      int q = tid >> 2, m = tid & 3, gq = q / 7;
      AgErot[q][m] = AgE[q][(m - gq + v + 8) & 3];
    }
    __syncthreads();

    // ---- pass B: denominators. Per-thread partial per q, shuffle-reduce.
    float arvE[kQR];
    float prt[kQR];
    if (tid < 196) {
#pragma unroll
      for (int gq = 0; gq < 4; ++gq) {
#pragma unroll
        for (int jq = 0; jq < 7; ++jq) {
          const int q = gq*7 + jq;
          const int db = ll - (jhalf*7 + jq);
          const int ai = s1a*da + s1b*db, ci = s2a*da + s2b*db;
          arvE[q] = exp2f(Arr2[q][13 + ai] + Acl2[q][13 + ci]);
          float e0 = __bfloat162float(contl[q][0*196 + tid]);
          float e1 = __bfloat162float(contl[q][1*196 + tid]);
          float e2 = __bfloat162float(contl[q][2*196 + tid]);
          float e3 = __bfloat162float(contl[q][3*196 + tid]);
          prt[q] = (e0*AgErot[q][0] + e1*AgErot[q][1] +
                    e2*AgErot[q][2] + e3*AgErot[q][3]) * arvE[q];
        }
      }
    } else {
#pragma unroll
      for (int q = 0; q < kQR; ++q) { prt[q] = 0.f; arvE[q] = 0.f; }
    }
#pragma unroll
    for (int q = 0; q < kQR; ++q) {
      float s = prt[q];
#pragma unroll
      for (int off = 1; off < 64; off <<= 1) s += __shfl_xor(s, off, 64);
      if ((tid & 63) == 0) redw[q][tid >> 6] = s;
    }
    __syncthreads();
    if (tid < kQR)
      DinvS[tid] = 1.0f / (redw[tid][0] + redw[tid][1] + redw[tid][2] + redw[tid][3]);
    __syncthreads();

    // ---- pass C: normalized probs (no transcendentals), summed over g.
    // Stored bf16, row stride 800 (MFMA A-operand layout for k_pv).
    if (tid < 196) {
      __hip_bfloat16* pbase =
          Pb + ((size_t)((bh*4 + v)*kSS + qi*14 + jhalf*7))*kKeyP + tid;
#pragma unroll
      for (int jq = 0; jq < 7; ++jq) {
        float am[4] = {0.f, 0.f, 0.f, 0.f};
#pragma unroll
        for (int gq = 0; gq < 4; ++gq) {
          const int q = gq*7 + jq;
          const float fq = arvE[q] * DinvS[q];
          float e0 = __bfloat162float(contl[q][0*196 + tid]);
          float e1 = __bfloat162float(contl[q][1*196 + tid]);
          float e2 = __bfloat162float(contl[q][2*196 + tid]);
          float e3 = __bfloat162float(contl[q][3*196 + tid]);
          am[0] += e0 * (AgErot[q][0] * fq);
          am[1] += e1 * (AgErot[q][1] * fq);
          am[2] += e2 * (AgErot[q][2] * fq);
          am[3] += e3 * (AgErot[q][3] * fq);
        }
        __hip_bfloat16* pp = pbase + (size_t)jq*kKeyP;
#pragma unroll
        for (int m = 0; m < 4; ++m) pp[m*196] = __float2bfloat16(am[m]);
      }
    }
    // zero the key-pad [784,800) of this block's 7 rows for this v
    if (tid < 112) {
      int jq = tid >> 4, kp = tid & 15;
      Pb[((size_t)((bh*4 + v)*kSS + qi*14 + jhalf*7 + jq))*kKeyP + kKey + kp] =
          __float2bfloat16(0.f);
    }
    __syncthreads();   // protects AgErot for next v
  }
}

// ============================================================
// Kernel 4: PV GEMM via bf16 MFMA, zero LDS, zero barriers (R5-proven).
// Block = (bh, M-tile of 16 rows of (v,ij)); D[16x96] = P[16x800] * V[800x96].
// ============================================================
__global__ __launch_bounds__(128)
void k_pv(const __hip_bfloat16* __restrict__ Pb,
          const __hip_bfloat16* __restrict__ Vb, float* __restrict__ vo) {
  const int tid  = threadIdx.x;
  const int lane = tid & 63;
  const int wave = tid >> 6;
  const int bh = blockIdx.x / 49;
  const int mt = blockIdx.x % 49;
  const int mrow = lane & 15;
  const int quad = lane >> 4;

  const short* Ap = (const short*)Pb +
      ((size_t)(bh*kKey + mt*16 + mrow))*kKeyP + quad*8;
  const short* Bp = (const short*)Vb + ((size_t)bh*96)*kKeyP + quad*8;

  f32x4 acc0 = {0.f,0.f,0.f,0.f};
  f32x4 acc1 = {0.f,0.f,0.f,0.f};
  f32x4 acc2 = {0.f,0.f,0.f,0.f};

  const int n0 = (wave*3 + 0)*16 + mrow;
  const int n1 = (wave*3 + 1)*16 + mrow;
  const int n2 = (wave*3 + 2)*16 + mrow;

  for (int ks = 0; ks < kKeyP/32; ++ks) {
    bf16x8 a  = *(const bf16x8*)(Ap + ks*32);
    bf16x8 b0 = *(const bf16x8*)(Bp + (size_t)n0*kKeyP + ks*32);
    bf16x8 b1 = *(const bf16x8*)(Bp + (size_t)n1*kKeyP + ks*32);
    bf16x8 b2 = *(const bf16x8*)(Bp + (size_t)n2*kKeyP + ks*32);
    acc0 = __builtin_amdgcn_mfma_f32_16x16x32_bf16(a, b0, acc0, 0, 0, 0);
    acc1 = __builtin_amdgcn_mfma_f32_16x16x32_bf16(a, b1, acc1, 0, 0, 0);
    acc2 = __builtin_amdgcn_mfma_f32_16x16x32_bf16(a, b2, acc2, 0, 0, 0);
  }

  const int b_ = bh >> 3, h_ = bh & 7;
#pragma unroll
  for (int r = 0; r < 4; ++r) {
    int m  = mt*16 + quad*4 + r;
    int v  = m / kSS, ij = m % kSS;
    float* op = vo + ((size_t)((b_*4 + v)*kSS + ij))*768 + h_;
    op[(size_t)(n0)*8] = acc0[r];
    op[(size_t)(n1)*8] = acc1[r];
    op[(size_t)(n2)*8] = acc2[r];
  }
}

// ============================================================
// Kernel 5: output projection, d-range split over grid.y (224 blocks).
// out[b][d][v][ij] = Wo[d] . vo[b,v,ij,:] + bo[d]
// ============================================================
__global__ __launch_bounds__(256)
void k_outproj(const float* __restrict__ vo, const float* __restrict__ Wo,
               const float* __restrict__ bo, float* __restrict__ out) {
  const int tid = threadIdx.x;
  const int bid = blockIdx.x;
  const int dhalf = blockIdx.y;
  const int i = bid % 14;
  const int v = (bid / 14) & 3;
  const int b = bid / 56;

  __shared__ alignas(16) float vos[14][772];
  const float* src = vo + ((size_t)((b*4 + v)*kSS + i*14))*768;
  for (int idx = tid; idx < 14*768; idx += 256)
    vos[idx / 768][idx % 768] = src[idx];
  __syncthreads();

  for (int oi = tid; oi < 48*14; oi += 256) {
    int d = dhalf*48 + oi / 14, j = oi % 14;
    const float* wrow = Wo + (size_t)d*768;
    float a = bo[d];
    for (int c = 0; c < 768; c += 4) {
      float4 w = *(const float4*)(wrow + c);
      float4 vv = *(const float4*)(&vos[j][c]);
      a += w.x*vv.x + w.y*vv.y + w.z*vv.z + w.w*vv.w;
    }
    out[((size_t)(b*96 + d)*4 + v)*kSS + i*14 + j] = a;
  }
}

// ============================================================
extern "C" void kernel_launch(void* const* d_in, const int* in_sizes, int n_in,
                              void* d_out, int out_size, void* d_ws, size_t ws_size,
                              hipStream_t stream) {
  const float* x    = (const float*)d_in[0];
  const float* Wq   = (const float*)d_in[1];
  const float* bq   = (const float*)d_in[2];
  const float* Wk   = (const float*)d_in[3];
  const float* bk   = (const float*)d_in[4];
  const float* Wv   = (const float*)d_in[5];
  const float* bv   = (const float*)d_in[6];
  const float* Wo   = (const float*)d_in[7];
  const float* bo   = (const float*)d_in[8];
  const float* rw1  = (const float*)d_in[9];
  const float* rb1  = (const float*)d_in[10];
  const float* rgam = (const float*)d_in[11];
  const float* rbet = (const float*)d_in[12];
  const float* rw2  = (const float*)d_in[13];
  const float* rb2  = (const float*)d_in[14];
  const float* cw1  = (const float*)d_in[15];
  const float* cb1  = (const float*)d_in[16];
  const float* cgam = (const float*)d_in[17];
  const float* cbet = (const float*)d_in[18];
  const float* cw2  = (const float*)d_in[19];
  const float* cb2  = (const float*)d_in[20];
  const float* gemb = (const float*)d_in[21];
  // d_in[22..24] = row_rel, col_rel, g_idx: reconstructed analytically.

  float* ws = (float*)d_ws;
  __hip_bfloat16* Qb = (__hip_bfloat16*)(ws + OFF_Qb);
  __hip_bfloat16* Kb = (__hip_bfloat16*)(ws + OFF_Kb);
  __hip_bfloat16* Vb = (__hip_bfloat16*)(ws + OFF_V);
  float* Frow = ws + OFF_FR;
  float* Fcol = ws + OFF_FC;
  __hip_bfloat16* Pb = (__hip_bfloat16*)(ws + OFF_PS);
  float* VO   = ws + OFF_VO;
  float* out  = (float*)d_out;

  k_setup<<<17, 256, 0, stream>>>(rw1, rb1, rgam, rbet, rw2, rb2,
                                  cw1, cb1, cgam, cbet, cw2, cb2,
                                  Frow, Fcol, Vb);
  k_qkv<<<dim3(112, 3), 256, 0, stream>>>(x, Wq, bq, Wk, bk, Wv, bv, Qb, Kb, Vb);
  k_attn<<<448, 256, 0, stream>>>(Qb, Kb, Frow, Fcol, gemb, Pb);
  k_pv<<<784, 128, 0, stream>>>(Pb, Vb, VO);
  k_outproj<<<dim3(112, 2), 256, 0, stream>>>(VO, Wo, bo, out);
}

// Round 9
// 264.033 us; speedup vs baseline: 1.5248x; 1.0255x over previous
//
#include <hip/hip_runtime.h>
#include <hip/hip_bf16.h>

// Problem constants
constexpr int kB   = 2;
constexpr int kH   = 8;
constexpr int kG   = 4;
constexpr int kS   = 14;
constexpr int kSS  = 196;   // S*S
constexpr int kKey = 784;   // G*S*S keys per (b,h)
constexpr int kKeyP = 800;  // keys padded to multiple of 32 for MFMA K-loop
constexpr int kMid = 96;
constexpr int kQR  = 28;    // 4 g * 7 j query rows per attention block
constexpr int kCL  = 788;   // contl row stride in u16 = 197*4 ([ij][m] interleaved)
constexpr float kScl = 0.10206207261596577f; // 1/sqrt(96)
constexpr float kK2  = 0.14724663682f;       // kScl / ln(2)  (exp2 domain)
constexpr float kCc  = 11.5415603272f;       // 8 nats / ln(2): constant softmax shift (exact)

typedef __attribute__((ext_vector_type(8))) short bf16x8;
typedef __attribute__((ext_vector_type(4))) float f32x4;

// ---------------- workspace layout (float elements) ----------------
constexpr size_t SZ_QKb = (size_t)kB*kH*kG*kSS*kMid/2; // 602,112 (bf16 in float units)
constexpr size_t OFF_Qb = 0;                            // Qb bf16 [bh][g*196+ij][96]
constexpr size_t OFF_Kb = OFF_Qb + SZ_QKb;              // Kb bf16 [bh][g*196+ij][96]
constexpr size_t OFF_V  = OFF_Kb + SZ_QKb;              // Vb bf16 CHANNEL-MAJOR [bh][c][800]
constexpr size_t SZ_V   = (size_t)kB*kH*kMid*kKeyP/2;   // 614,400
constexpr size_t OFF_FR = OFF_V + SZ_V;                 // 27*32 row table fp32
constexpr size_t OFF_FC = OFF_FR + 27*32;               // 27*32 col table fp32
constexpr size_t OFF_PS = OFF_FC + 27*32;               // Psum bf16 [bh][v*196+ij][800]
constexpr size_t SZ_PS  = (size_t)kB*kH*kG*kSS*kKeyP/2; // 5,017,600
// (vo not materialized in global: fused into k_pvo)

// ============================================================
// Kernel 1: QKV projection + fused setup.
// Q,K bf16 key-major [bh][g*196+ij][96] (MFMA A/B^T layout for k_attn).
// V bf16 CHANNEL-MAJOR [bh][c][800] (MFMA B layout for k_pvo).
// d = c*8 + h per the reference reshape(MID, HEADS).
// Fused tails: ten==2 blocks bid<16 zero V key-pad; ten==0 bid==0 computes
// the 27x32 embed tables (row_rel/col_rel take only values n/13).
// ============================================================
__global__ __launch_bounds__(256)
void k_qkv(const float* __restrict__ x,
           const float* __restrict__ Wq, const float* __restrict__ bq,
           const float* __restrict__ Wk, const float* __restrict__ bk,
           const float* __restrict__ Wv, const float* __restrict__ bv,
           __hip_bfloat16* __restrict__ Qb, __hip_bfloat16* __restrict__ Kb,
           __hip_bfloat16* __restrict__ Vb,
           const float* __restrict__ rw1, const float* __restrict__ rb1,
           const float* __restrict__ rgam, const float* __restrict__ rbet,
           const float* __restrict__ rw2, const float* __restrict__ rb2,
           const float* __restrict__ cw1, const float* __restrict__ cb1,
           const float* __restrict__ cgam, const float* __restrict__ cbet,
           const float* __restrict__ cw2, const float* __restrict__ cb2,
           float* __restrict__ frow, float* __restrict__ fcol) {
  const int bid = blockIdx.x;
  const int ten = blockIdx.y;
  const int i = bid % 14;
  const int g = (bid / 14) % 4;
  const int b = bid / 56;
  const float* W    = (ten == 0) ? Wq : (ten == 1) ? Wk : Wv;
  const float* bias = (ten == 0) ? bq : (ten == 1) ? bk : bv;

  __shared__ alignas(16) float xs[14][100];   // transposed, padded
  for (int idx = threadIdx.x; idx < 96*14; idx += 256) {
    int cin = idx / 14, j = idx % 14;
    xs[j][cin] = x[((size_t)(b*96 + cin)*4 + g)*196 + i*14 + j];
  }
  __syncthreads();

  for (int d = threadIdx.x; d < 768; d += 256) {
    int c = d >> 3, h = d & 7;
    float bvv = bias[d];
    float acc[14];
#pragma unroll
    for (int j = 0; j < 14; ++j) acc[j] = bvv;
    const float* wrow = W + (size_t)d * 96;
    for (int cc = 0; cc < 96; cc += 4) {
      float4 w = *(const float4*)(wrow + cc);
#pragma unroll
      for (int j = 0; j < 14; ++j) {
        float4 xv = *(const float4*)(&xs[j][cc]);
        acc[j] += w.x*xv.x + w.y*xv.y + w.z*xv.z + w.w*xv.w;
      }
    }
    if (ten == 2) {
      __hip_bfloat16* op = Vb + ((size_t)((b*8 + h)*96 + c))*kKeyP + g*196 + i*14;
#pragma unroll
      for (int j = 0; j < 14; ++j) op[j] = __float2bfloat16(acc[j]);
    } else {
      __hip_bfloat16* dst = (ten == 0) ? Qb : Kb;
      __hip_bfloat16* op = dst + ((size_t)((b*8 + h)*4 + g)*196 + i*14)*96 + c;
#pragma unroll
      for (int j = 0; j < 14; ++j) op[(size_t)j*96] = __float2bfloat16(acc[j]);
    }
  }

  // ---- fused setup tails ----
  if (ten == 2 && bid < 16) {
    // zero V key-pad for bh = bid
    for (int idx = threadIdx.x; idx < 96*16; idx += 256) {
      int c = idx >> 4, kp = idx & 15;
      Vb[((size_t)(bid*96 + c))*kKeyP + kKey + kp] = __float2bfloat16(0.f);
    }
  }
  if (ten == 0 && bid == 0 && threadIdx.x < 54) {
    int t = threadIdx.x;
    int which = t / 27;
    int n = t % 27;
    float tv = (float)(n - 13) / 13.0f;
    const float* w1  = which ? cw1  : rw1;
    const float* b1  = which ? cb1  : rb1;
    const float* gam = which ? cgam : rgam;
    const float* bet = which ? cbet : rbet;
    const float* w2  = which ? cw2  : rw2;
    const float* b2  = which ? cb2  : rb2;
    float h[16];
    float mu = 0.f;
#pragma unroll
    for (int d = 0; d < 16; ++d) { h[d] = tv * w1[d] + b1[d]; mu += h[d]; }
    mu *= (1.0f/16.0f);
    float var = 0.f;
#pragma unroll
    for (int d = 0; d < 16; ++d) { float z = h[d] - mu; var += z*z; }
    var *= (1.0f/16.0f);
    float rstd = rsqrtf(var + 1e-5f);
#pragma unroll
    for (int d = 0; d < 16; ++d) {
      float z = (h[d] - mu) * rstd * gam[d] + bet[d];
      h[d] = z / (1.0f + expf(-z));   // silu
    }
    float* outp = (which ? fcol : frow) + n*32;
    for (int c = 0; c < 32; ++c) {
      float o = b2[c];
#pragma unroll
      for (int d = 0; d < 16; ++d) o += h[d] * w2[d*32 + c];
      outp[c] = o;
    }
  }
}

// ============================================================
// Kernel 2: fused content + bias + softmax (same as R8).
// MFMA QK^T -> contl stored [q][ij*4 + m]; softmax passes read ushort4.
// Denominator reduction level-outer with q unrolled (ILP).
// Block = (b,h,i,jhalf): 28 query rows (4 g x 7 j) vs 784 keys.
// ============================================================
__global__ __launch_bounds__(256, 2)
void k_attn(const __hip_bfloat16* __restrict__ Qb, const __hip_bfloat16* __restrict__ Kb,
            const float* __restrict__ frow_g, const float* __restrict__ fcol_g,
            const float* __restrict__ gemb_g, __hip_bfloat16* __restrict__ Pb) {
  const int tid = threadIdx.x;
  const int bid = blockIdx.x;
  const int jhalf = bid & 1;
  const int t2 = bid >> 1;
  const int qi = t2 % 14;
  const int hh = (t2 / 14) % 8;
  const int bb = t2 / 112;
  const int bh = bb*8 + hh;

  __shared__ alignas(16) float qs[kQR][96];   // fp32 copies for bias dots
  __shared__ alignas(16) float frowS[27*32];
  __shared__ alignas(16) float fcolS[27*32];
  __shared__ alignas(16) float gembS[128];
  __shared__ float Arr2[kQR][27];             // row bias dot, pre-scaled by kK2
  __shared__ float Acl2[kQR][27];             // col bias dot, pre-scaled by kK2
  __shared__ float AgE[kQR][4];               // exp2(group bias * kK2)
  __shared__ float AgErot[kQR][4];            // per-v rotated AgE
  __shared__ float redw[kQR][4];
  __shared__ float DinvS[kQR];
  __shared__ alignas(16) __hip_bfloat16 contl[kQR][kCL];  // E: [q][ij*4 + m]

  const short* Qs = (const short*)Qb;
  const short* Ks = (const short*)Kb;

  // ---- stage fp32 query copies + tables (tables pre-scaled into exp2 domain)
  for (int idx = tid; idx < kQR*96; idx += 256) {
    int q = idx / 96, c = idx - q*96;
    int g = q / 7, jq = q - g*7;
    qs[q][c] = __bfloat162float(
        Qb[((size_t)((bh*4 + g)*kSS + qi*14 + jhalf*7 + jq))*96 + c]);
  }
  for (int idx = tid; idx < 864; idx += 256) frowS[idx] = frow_g[idx] * kK2;
  for (int idx = tid; idx < 864; idx += 256) fcolS[idx] = fcol_g[idx] * kK2;
  if (tid < 128) gembS[tid] = gemb_g[tid] * kK2;
  __syncthreads();

  // ---- MFMA content GEMM -> contl (E = exp2(content*kK2 - Cc), bf16)
  {
    const int lane = tid & 63;
    const int wave = tid >> 6;
    const int col  = lane & 15;
    const int quad = lane >> 4;

    bf16x8 afrag[2][3];
#pragma unroll
    for (int mt = 0; mt < 2; ++mt) {
      int m = mt*16 + col;
      int q = (m < kQR) ? m : 0;                 // pad rows: duplicate q0 (discarded)
      const short* qrow = Qs +
          ((size_t)((bh*4 + q/7)*kSS + qi*14 + jhalf*7 + q%7))*96;
#pragma unroll
      for (int ks = 0; ks < 3; ++ks)
        afrag[mt][ks] = *(const bf16x8*)(qrow + ks*32 + quad*8);
    }

    for (int nt = wave; nt < 49; nt += 4) {
      int kl = nt*16 + col;                      // key index g_key*196 + ij
      const short* krow = Ks + ((size_t)(bh*kKey + kl))*96;
      bf16x8 b0 = *(const bf16x8*)(krow + 0*32 + quad*8);
      bf16x8 b1 = *(const bf16x8*)(krow + 1*32 + quad*8);
      bf16x8 b2 = *(const bf16x8*)(krow + 2*32 + quad*8);
      f32x4 c0 = {0.f,0.f,0.f,0.f};
      f32x4 c1 = {0.f,0.f,0.f,0.f};
      c0 = __builtin_amdgcn_mfma_f32_16x16x32_bf16(afrag[0][0], b0, c0, 0, 0, 0);
      c0 = __builtin_amdgcn_mfma_f32_16x16x32_bf16(afrag[0][1], b1, c0, 0, 0, 0);
      c0 = __builtin_amdgcn_mfma_f32_16x16x32_bf16(afrag[0][2], b2, c0, 0, 0, 0);
      c1 = __builtin_amdgcn_mfma_f32_16x16x32_bf16(afrag[1][0], b0, c1, 0, 0, 0);
      c1 = __builtin_amdgcn_mfma_f32_16x16x32_bf16(afrag[1][1], b1, c1, 0, 0, 0);
      c1 = __builtin_amdgcn_mfma_f32_16x16x32_bf16(afrag[1][2], b2, c1, 0, 0, 0);
      int ijn = kl % 196, mk = kl / 196;         // interleaved store position
      // C/D layout: col = lane&15 (=kl), row = quad*4 + r (=q)  [m89]
#pragma unroll
      for (int r = 0; r < 4; ++r) {
        int q0 = quad*4 + r;                     // 0..15, all valid
        contl[q0][ijn*4 + mk] = __float2bfloat16(exp2f(c0[r]*kK2 - kCc));
        int q1 = 16 + quad*4 + r;                // 16..31, valid < 28
        if (q1 < kQR)
          contl[q1][ijn*4 + mk] = __float2bfloat16(exp2f(c1[r]*kK2 - kCc));
      }
    }
  }

  // ---- per-query bias tables (exp2 domain)
  for (int t = tid; t < kQR*58; t += 256) {
    int q = t / 58, s = t - q*58;
    float acc = 0.f;
    if (s < 27) {
#pragma unroll
      for (int c = 0; c < 32; ++c) acc += qs[q][c] * frowS[s*32 + c];
      Arr2[q][s] = acc;
    } else if (s < 54) {
      int n = s - 27;
#pragma unroll
      for (int c = 0; c < 32; ++c) acc += qs[q][32+c] * fcolS[n*32 + c];
      Acl2[q][n] = acc;
    } else {
      int p = s - 54;
#pragma unroll
      for (int c = 0; c < 32; ++c) acc += qs[q][64+c] * gembS[p*32 + c];
      AgE[q][p] = exp2f(acc);
    }
  }
  __syncthreads();

  const int kk = (tid < 196) ? (tid / 14) : 0;
  const int ll = (tid < 196) ? (tid % 14) : 0;
  const int da = kk - qi;

  for (int v = 0; v < 4; ++v) {
    int s1a, s1b, s2a, s2b;
    if (v == 0)      { s1a = 1;  s1b = 0;  s2a = 0;  s2b = 1;  }
    else if (v == 1) { s1a = 0;  s1b = -1; s2a = 1;  s2b = 0;  }
    else if (v == 2) { s1a = -1; s1b = 0;  s2a = 0;  s2b = -1; }
    else             { s1a = 0;  s1b = 1;  s2a = -1; s2b = 0;  }

    if (tid < 112) {
      int q = tid >> 2, m = tid & 3, gq = q / 7;
      AgErot[q][m] = AgE[q][(m - gq + v + 8) & 3];
    }
    __syncthreads();

    // ---- pass B: denominators. Vectorized contl read, ILP shuffle-reduce.
    float arvE[kQR];
    float prt[kQR];
    if (tid < 196) {
#pragma unroll
      for (int gq = 0; gq < 4; ++gq) {
#pragma unroll
        for (int jq = 0; jq < 7; ++jq) {
          const int q = gq*7 + jq;
          const int db = ll - (jhalf*7 + jq);
          const int ai = s1a*da + s1b*db, ci = s2a*da + s2b*db;
          arvE[q] = exp2f(Arr2[q][13 + ai] + Acl2[q][13 + ci]);
          ushort4 u = *(const ushort4*)(&contl[q][tid*4]);
          float e0 = __uint_as_float((unsigned)u.x << 16);
          float e1 = __uint_as_float((unsigned)u.y << 16);
          float e2 = __uint_as_float((unsigned)u.z << 16);
          float e3 = __uint_as_float((unsigned)u.w << 16);
          prt[q] = (e0*AgErot[q][0] + e1*AgErot[q][1] +
                    e2*AgErot[q][2] + e3*AgErot[q][3]) * arvE[q];
        }
      }
    } else {
#pragma unroll
      for (int q = 0; q < kQR; ++q) { prt[q] = 0.f; arvE[q] = 0.f; }
    }
    // level-outer butterfly: 28 independent shuffles per level (ILP)
#pragma unroll
    for (int off = 1; off < 64; off <<= 1) {
#pragma unroll
      for (int q = 0; q < kQR; ++q)
        prt[q] += __shfl_xor(prt[q], off, 64);
    }
    if ((tid & 63) == 0) {
#pragma unroll
      for (int q = 0; q < kQR; ++q) redw[q][tid >> 6] = prt[q];
    }
    __syncthreads();
    if (tid < kQR)
      DinvS[tid] = 1.0f / (redw[tid][0] + redw[tid][1] + redw[tid][2] + redw[tid][3]);
    __syncthreads();

    // ---- pass C: normalized probs (no transcendentals), summed over g.
    // Stored bf16, row stride 800 (MFMA A-operand layout for k_pvo).
    if (tid < 196) {
      __hip_bfloat16* pbase =
          Pb + ((size_t)((bh*4 + v)*kSS + qi*14 + jhalf*7))*kKeyP + tid;
#pragma unroll
      for (int jq = 0; jq < 7; ++jq) {
        float am[4] = {0.f, 0.f, 0.f, 0.f};
#pragma unroll
        for (int gq = 0; gq < 4; ++gq) {
          const int q = gq*7 + jq;
          const float fq = arvE[q] * DinvS[q];
          ushort4 u = *(const ushort4*)(&contl[q][tid*4]);
          float e0 = __uint_as_float((unsigned)u.x << 16);
          float e1 = __uint_as_float((unsigned)u.y << 16);
          float e2 = __uint_as_float((unsigned)u.z << 16);
          float e3 = __uint_as_float((unsigned)u.w << 16);
          am[0] += e0 * (AgErot[q][0] * fq);
          am[1] += e1 * (AgErot[q][1] * fq);
          am[2] += e2 * (AgErot[q][2] * fq);
          am[3] += e3 * (AgErot[q][3] * fq);
        }
        __hip_bfloat16* pp = pbase + (size_t)jq*kKeyP;
#pragma unroll
        for (int m = 0; m < 4; ++m) pp[m*196] = __float2bfloat16(am[m]);
      }
    }
    // zero the key-pad [784,800) of this block's 7 rows for this v
    if (tid < 112) {
      int jq = tid >> 4, kp = tid & 15;
      Pb[((size_t)((bh*4 + v)*kSS + qi*14 + jhalf*7 + jq))*kKeyP + kKey + kp] =
          __float2bfloat16(0.f);
    }
    __syncthreads();   // protects AgErot for next v
  }
}

// ============================================================
// Kernel 3: fused PV + output projection, all MFMA.
// Block = (b, 16-row M-tile of (v,ij) space): 2 x 49 = 98 blocks, 256 thr.
// Phase 1: per wave 2 heads: vo[16x96] = P[16x800] . V[800x96] -> bf16 LDS,
//   stored with the REFERENCE k-convention: column index = c*8 + h.
// Phase 2: out[16x96] = vo[16x768] . Wo^T (Wo fp32 -> bf16 on the fly) + bo
//   (Wo rows are laid out d-major with columns c*8+h -> contiguous reads).
// ============================================================
__global__ __launch_bounds__(256)
void k_pvo(const __hip_bfloat16* __restrict__ Pb,
           const __hip_bfloat16* __restrict__ Vb,
           const float* __restrict__ Wo, const float* __restrict__ bo,
           float* __restrict__ out) {
  const int tid  = threadIdx.x;
  const int lane = tid & 63;
  const int wave = tid >> 6;
  const int b_ = blockIdx.x / 49;
  const int mt = blockIdx.x % 49;
  const int mrow = lane & 15;
  const int quad = lane >> 4;

  __shared__ alignas(16) __hip_bfloat16 vos[16][776];  // [m-row][c*8+h], pad 768->776

  // ---- phase 1: PV for this block's 16 rows, per wave 2 heads
#pragma unroll
  for (int ho = 0; ho < 2; ++ho) {
    const int h = wave*2 + ho;
    const int bh = b_*8 + h;
    const short* Ap = (const short*)Pb +
        ((size_t)(bh*kKey + mt*16 + mrow))*kKeyP + quad*8;
    const short* Bp = (const short*)Vb + ((size_t)bh*96)*kKeyP + quad*8;
    f32x4 acc[6];
#pragma unroll
    for (int nt = 0; nt < 6; ++nt) acc[nt] = (f32x4){0.f,0.f,0.f,0.f};
    for (int ks = 0; ks < kKeyP/32; ++ks) {
      bf16x8 a = *(const bf16x8*)(Ap + ks*32);
#pragma unroll
      for (int nt = 0; nt < 6; ++nt) {
        bf16x8 bf = *(const bf16x8*)(Bp + (size_t)(nt*16 + mrow)*kKeyP + ks*32);
        acc[nt] = __builtin_amdgcn_mfma_f32_16x16x32_bf16(a, bf, acc[nt], 0, 0, 0);
      }
    }
    // C/D: col = lane&15 (= c within n-tile), row = quad*4 + r (= m-row)
    // Store with k = c*8 + h (reference MID*HEADS flattening) -- R8 bug was h*96+c.
#pragma unroll
    for (int nt = 0; nt < 6; ++nt)
#pragma unroll
      for (int r = 0; r < 4; ++r)
        vos[quad*4 + r][(nt*16 + mrow)*8 + h] = __float2bfloat16(acc[nt][r]);
  }
  __syncthreads();

  // ---- phase 2: out = vos . Wo^T + bo  (nt over 6 d-tiles of 16)
  for (int nt = wave; nt < 6; nt += 4) {
    const int d = nt*16 + mrow;
    const float* wrow = Wo + (size_t)d*768;
    f32x4 acc = {0.f,0.f,0.f,0.f};
    for (int ks = 0; ks < 24; ++ks) {
      bf16x8 a = *(const bf16x8*)(&vos[mrow][ks*32 + quad*8]);
      float4 w0 = *(const float4*)(wrow + ks*32 + quad*8);
      float4 w1 = *(const float4*)(wrow + ks*32 + quad*8 + 4);
      bf16x8 bf;
      __hip_bfloat16 t0 = __float2bfloat16(w0.x); bf[0] = *(short*)&t0;
      __hip_bfloat16 t1 = __float2bfloat16(w0.y); bf[1] = *(short*)&t1;
      __hip_bfloat16 t2 = __float2bfloat16(w0.z); bf[2] = *(short*)&t2;
      __hip_bfloat16 t3 = __float2bfloat16(w0.w); bf[3] = *(short*)&t3;
      __hip_bfloat16 t4 = __float2bfloat16(w1.x); bf[4] = *(short*)&t4;
      __hip_bfloat16 t5 = __float2bfloat16(w1.y); bf[5] = *(short*)&t5;
      __hip_bfloat16 t6 = __float2bfloat16(w1.z); bf[6] = *(short*)&t6;
      __hip_bfloat16 t7 = __float2bfloat16(w1.w); bf[7] = *(short*)&t7;
      acc = __builtin_amdgcn_mfma_f32_16x16x32_bf16(a, bf, acc, 0, 0, 0);
    }
    const float bod = bo[d];
    // D: col = lane&15 (= d within tile), row = quad*4 + r (= m-row)
#pragma unroll
    for (int r = 0; r < 4; ++r) {
      int m = mt*16 + quad*4 + r;
      int v = m / kSS, ij = m % kSS;
      out[((size_t)(b_*96 + d)*4 + v)*kSS + ij] = acc[r] + bod;
    }
  }
}

// ============================================================
extern "C" void kernel_launch(void* const* d_in, const int* in_sizes, int n_in,
                              void* d_out, int out_size, void* d_ws, size_t ws_size,
                              hipStream_t stream) {
  const float* x    = (const float*)d_in[0];
  const float* Wq   = (const float*)d_in[1];
  const float* bq   = (const float*)d_in[2];
  const float* Wk   = (const float*)d_in[3];
  const float* bk   = (const float*)d_in[4];
  const float* Wv   = (const float*)d_in[5];
  const float* bv   = (const float*)d_in[6];
  const float* Wo   = (const float*)d_in[7];
  const float* bo   = (const float*)d_in[8];
  const float* rw1  = (const float*)d_in[9];
  const float* rb1  = (const float*)d_in[10];
  const float* rgam = (const float*)d_in[11];
  const float* rbet = (const float*)d_in[12];
  const float* rw2  = (const float*)d_in[13];
  const float* rb2  = (const float*)d_in[14];
  const float* cw1  = (const float*)d_in[15];
  const float* cb1  = (const float*)d_in[16];
  const float* cgam = (const float*)d_in[17];
  const float* cbet = (const float*)d_in[18];
  const float* cw2  = (const float*)d_in[19];
  const float* cb2  = (const float*)d_in[20];
  const float* gemb = (const float*)d_in[21];
  // d_in[22..24] = row_rel, col_rel, g_idx: reconstructed analytically.

  float* ws = (float*)d_ws;
  __hip_bfloat16* Qb = (__hip_bfloat16*)(ws + OFF_Qb);
  __hip_bfloat16* Kb = (__hip_bfloat16*)(ws + OFF_Kb);
  __hip_bfloat16* Vb = (__hip_bfloat16*)(ws + OFF_V);
  float* Frow = ws + OFF_FR;
  float* Fcol = ws + OFF_FC;
  __hip_bfloat16* Pb = (__hip_bfloat16*)(ws + OFF_PS);
  float* out  = (float*)d_out;

  k_qkv<<<dim3(112, 3), 256, 0, stream>>>(x, Wq, bq, Wk, bk, Wv, bv, Qb, Kb, Vb,
                                          rw1, rb1, rgam, rbet, rw2, rb2,
                                          cw1, cb1, cgam, cbet, cw2, cb2,
                                          Frow, Fcol);
  k_attn<<<448, 256, 0, stream>>>(Qb, Kb, Frow, Fcol, gemb, Pb);
  k_pvo<<<98, 256, 0, stream>>>(Pb, Vb, Wo, bo, out);
}

// Round 10
// 224.299 us; speedup vs baseline: 1.7949x; 1.1771x over previous
//
#include <hip/hip_runtime.h>
#include <hip/hip_bf16.h>

// Problem constants
constexpr int kB   = 2;
constexpr int kH   = 8;
constexpr int kG   = 4;
constexpr int kS   = 14;
constexpr int kSS  = 196;   // S*S
constexpr int kKey = 784;   // G*S*S keys per (b,h)
constexpr int kKeyP = 800;  // keys padded to multiple of 32 for MFMA K-loop
constexpr int kMid = 96;
constexpr int kQR  = 28;    // 4 g * 7 j query rows per attention block
constexpr int kCL  = 788;   // contl row stride in u16 = 197*4 ([ij][m] interleaved)
constexpr float kScl = 0.10206207261596577f; // 1/sqrt(96)
constexpr float kK2  = 0.14724663682f;       // kScl / ln(2)  (exp2 domain)
constexpr float kCc  = 11.5415603272f;       // 8 nats / ln(2): constant softmax shift (exact)

typedef __attribute__((ext_vector_type(8))) short bf16x8;
typedef __attribute__((ext_vector_type(4))) float f32x4;

// ---------------- workspace layout (float elements) ----------------
constexpr size_t SZ_QKb = (size_t)kB*kH*kG*kSS*kMid/2; // 602,112 (bf16 in float units)
constexpr size_t OFF_Qb = 0;                            // Qb bf16 [bh][g*196+ij][96]
constexpr size_t OFF_Kb = OFF_Qb + SZ_QKb;              // Kb bf16 [bh][g*196+ij][96]
constexpr size_t OFF_V  = OFF_Kb + SZ_QKb;              // Vb bf16 CHANNEL-MAJOR [bh][c][800]
constexpr size_t SZ_V   = (size_t)kB*kH*kMid*kKeyP/2;   // 614,400
constexpr size_t OFF_FR = OFF_V + SZ_V;                 // 27*32 row table fp32
constexpr size_t OFF_FC = OFF_FR + 27*32;               // 27*32 col table fp32
constexpr size_t OFF_PS = OFF_FC + 27*32;               // Psum bf16 [bh][v*196+ij][800]
constexpr size_t SZ_PS  = (size_t)kB*kH*kG*kSS*kKeyP/2; // 5,017,600
constexpr size_t OFF_WOH = OFF_PS + SZ_PS;              // Woh bf16 [h][d][c] (73,728)

// ============================================================
// Kernel 1: QKV projection + fused setup.
// Q,K bf16 key-major [bh][g*196+ij][96] (MFMA A/B^T layout for k_attn).
// V bf16 CHANNEL-MAJOR [bh][c][800] (MFMA B layout for k_pv).
// d = c*8 + h per the reference reshape(MID, HEADS).
// Fused tails: all blocks zero d_out (k_pv accumulates with atomics);
// ten==1 blocks convert Wo -> per-head bf16 Woh[h][d][c] (= Wo[d][c*8+h]);
// ten==2 bid<16 zero V key-pad; ten==0 bid==0 computes the 27x32 embed tables.
// ============================================================
__global__ __launch_bounds__(256)
void k_qkv(const float* __restrict__ x,
           const float* __restrict__ Wq, const float* __restrict__ bq,
           const float* __restrict__ Wk, const float* __restrict__ bk,
           const float* __restrict__ Wv, const float* __restrict__ bv,
           __hip_bfloat16* __restrict__ Qb, __hip_bfloat16* __restrict__ Kb,
           __hip_bfloat16* __restrict__ Vb,
           const float* __restrict__ rw1, const float* __restrict__ rb1,
           const float* __restrict__ rgam, const float* __restrict__ rbet,
           const float* __restrict__ rw2, const float* __restrict__ rb2,
           const float* __restrict__ cw1, const float* __restrict__ cb1,
           const float* __restrict__ cgam, const float* __restrict__ cbet,
           const float* __restrict__ cw2, const float* __restrict__ cb2,
           float* __restrict__ frow, float* __restrict__ fcol,
           const float* __restrict__ Wo, __hip_bfloat16* __restrict__ Woh,
           float* __restrict__ out0) {
  const int bid = blockIdx.x;
  const int ten = blockIdx.y;
  const int i = bid % 14;
  const int g = (bid / 14) % 4;
  const int b = bid / 56;
  const float* W    = (ten == 0) ? Wq : (ten == 1) ? Wk : Wv;
  const float* bias = (ten == 0) ? bq : (ten == 1) ? bk : bv;

  // ---- zero d_out (atomically accumulated by k_pv; harness poisons it)
  {
    int zidx = (ten*112 + bid)*256 + threadIdx.x;   // 0 .. 86015
    if (zidx < 37632) ((float4*)out0)[zidx] = make_float4(0.f, 0.f, 0.f, 0.f);
  }

  __shared__ alignas(16) float xs[14][100];   // transposed, padded
  for (int idx = threadIdx.x; idx < 96*14; idx += 256) {
    int cin = idx / 14, j = idx % 14;
    xs[j][cin] = x[((size_t)(b*96 + cin)*4 + g)*196 + i*14 + j];
  }
  __syncthreads();

  for (int d = threadIdx.x; d < 768; d += 256) {
    int c = d >> 3, h = d & 7;
    float bvv = bias[d];
    float acc[14];
#pragma unroll
    for (int j = 0; j < 14; ++j) acc[j] = bvv;
    const float* wrow = W + (size_t)d * 96;
    for (int cc = 0; cc < 96; cc += 4) {
      float4 w = *(const float4*)(wrow + cc);
#pragma unroll
      for (int j = 0; j < 14; ++j) {
        float4 xv = *(const float4*)(&xs[j][cc]);
        acc[j] += w.x*xv.x + w.y*xv.y + w.z*xv.z + w.w*xv.w;
      }
    }
    if (ten == 2) {
      __hip_bfloat16* op = Vb + ((size_t)((b*8 + h)*96 + c))*kKeyP + g*196 + i*14;
#pragma unroll
      for (int j = 0; j < 14; ++j) op[j] = __float2bfloat16(acc[j]);
    } else {
      __hip_bfloat16* dst = (ten == 0) ? Qb : Kb;
      __hip_bfloat16* op = dst + ((size_t)((b*8 + h)*4 + g)*196 + i*14)*96 + c;
#pragma unroll
      for (int j = 0; j < 14; ++j) op[(size_t)j*96] = __float2bfloat16(acc[j]);
    }
  }

  // ---- fused setup tails ----
  if (ten == 1) {
    // Woh[h][d][c] = bf16(Wo[d][c*8+h]) -- per-head B-operand for k_pv phase B
    for (int idx = bid*256 + threadIdx.x; idx < 73728; idx += 112*256) {
      int h = idx / 9216, rem = idx - h*9216;
      int d = rem / 96, c = rem - d*96;
      Woh[idx] = __float2bfloat16(Wo[(size_t)d*768 + c*8 + h]);
    }
  }
  if (ten == 2 && bid < 16) {
    // zero V key-pad for bh = bid
    for (int idx = threadIdx.x; idx < 96*16; idx += 256) {
      int c = idx >> 4, kp = idx & 15;
      Vb[((size_t)(bid*96 + c))*kKeyP + kKey + kp] = __float2bfloat16(0.f);
    }
  }
  if (ten == 0 && bid == 0 && threadIdx.x < 54) {
    int t = threadIdx.x;
    int which = t / 27;
    int n = t % 27;
    float tv = (float)(n - 13) / 13.0f;
    const float* w1  = which ? cw1  : rw1;
    const float* b1  = which ? cb1  : rb1;
    const float* gam = which ? cgam : rgam;
    const float* bet = which ? cbet : rbet;
    const float* w2  = which ? cw2  : rw2;
    const float* b2  = which ? cb2  : rb2;
    float h[16];
    float mu = 0.f;
#pragma unroll
    for (int d = 0; d < 16; ++d) { h[d] = tv * w1[d] + b1[d]; mu += h[d]; }
    mu *= (1.0f/16.0f);
    float var = 0.f;
#pragma unroll
    for (int d = 0; d < 16; ++d) { float z = h[d] - mu; var += z*z; }
    var *= (1.0f/16.0f);
    float rstd = rsqrtf(var + 1e-5f);
#pragma unroll
    for (int d = 0; d < 16; ++d) {
      float z = (h[d] - mu) * rstd * gam[d] + bet[d];
      h[d] = z / (1.0f + expf(-z));   // silu
    }
    float* outp = (which ? fcol : frow) + n*32;
    for (int c = 0; c < 32; ++c) {
      float o = b2[c];
#pragma unroll
      for (int d = 0; d < 16; ++d) o += h[d] * w2[d*32 + c];
      outp[c] = o;
    }
  }
}

// ============================================================
// Kernel 2: fused content + bias + softmax (R9-proven, unchanged).
// MFMA QK^T -> contl [q][ij*4+m]; level-outer ILP shuffle reduction.
// Block = (b,h,i,jhalf): 28 query rows (4 g x 7 j) vs 784 keys.
// ============================================================
__global__ __launch_bounds__(256, 2)
void k_attn(const __hip_bfloat16* __restrict__ Qb, const __hip_bfloat16* __restrict__ Kb,
            const float* __restrict__ frow_g, const float* __restrict__ fcol_g,
            const float* __restrict__ gemb_g, __hip_bfloat16* __restrict__ Pb) {
  const int tid = threadIdx.x;
  const int bid = blockIdx.x;
  const int jhalf = bid & 1;
  const int t2 = bid >> 1;
  const int qi = t2 % 14;
  const int hh = (t2 / 14) % 8;
  const int bb = t2 / 112;
  const int bh = bb*8 + hh;

  __shared__ alignas(16) float qs[kQR][96];   // fp32 copies for bias dots
  __shared__ alignas(16) float frowS[27*32];
  __shared__ alignas(16) float fcolS[27*32];
  __shared__ alignas(16) float gembS[128];
  __shared__ float Arr2[kQR][27];             // row bias dot, pre-scaled by kK2
  __shared__ float Acl2[kQR][27];             // col bias dot, pre-scaled by kK2
  __shared__ float AgE[kQR][4];               // exp2(group bias * kK2)
  __shared__ float AgErot[kQR][4];            // per-v rotated AgE
  __shared__ float redw[kQR][4];
  __shared__ float DinvS[kQR];
  __shared__ alignas(16) __hip_bfloat16 contl[kQR][kCL];  // E: [q][ij*4 + m]

  const short* Qs = (const short*)Qb;
  const short* Ks = (const short*)Kb;

  // ---- stage fp32 query copies + tables (tables pre-scaled into exp2 domain)
  for (int idx = tid; idx < kQR*96; idx += 256) {
    int q = idx / 96, c = idx - q*96;
    int g = q / 7, jq = q - g*7;
    qs[q][c] = __bfloat162float(
        Qb[((size_t)((bh*4 + g)*kSS + qi*14 + jhalf*7 + jq))*96 + c]);
  }
  for (int idx = tid; idx < 864; idx += 256) frowS[idx] = frow_g[idx] * kK2;
  for (int idx = tid; idx < 864; idx += 256) fcolS[idx] = fcol_g[idx] * kK2;
  if (tid < 128) gembS[tid] = gemb_g[tid] * kK2;
  __syncthreads();

  // ---- MFMA content GEMM -> contl (E = exp2(content*kK2 - Cc), bf16)
  {
    const int lane = tid & 63;
    const int wave = tid >> 6;
    const int col  = lane & 15;
    const int quad = lane >> 4;

    bf16x8 afrag[2][3];
#pragma unroll
    for (int mt = 0; mt < 2; ++mt) {
      int m = mt*16 + col;
      int q = (m < kQR) ? m : 0;                 // pad rows: duplicate q0 (discarded)
      const short* qrow = Qs +
          ((size_t)((bh*4 + q/7)*kSS + qi*14 + jhalf*7 + q%7))*96;
#pragma unroll
      for (int ks = 0; ks < 3; ++ks)
        afrag[mt][ks] = *(const bf16x8*)(qrow + ks*32 + quad*8);
    }

    for (int nt = wave; nt < 49; nt += 4) {
      int kl = nt*16 + col;                      // key index g_key*196 + ij
      const short* krow = Ks + ((size_t)(bh*kKey + kl))*96;
      bf16x8 b0 = *(const bf16x8*)(krow + 0*32 + quad*8);
      bf16x8 b1 = *(const bf16x8*)(krow + 1*32 + quad*8);
      bf16x8 b2 = *(const bf16x8*)(krow + 2*32 + quad*8);
      f32x4 c0 = {0.f,0.f,0.f,0.f};
      f32x4 c1 = {0.f,0.f,0.f,0.f};
      c0 = __builtin_amdgcn_mfma_f32_16x16x32_bf16(afrag[0][0], b0, c0, 0, 0, 0);
      c0 = __builtin_amdgcn_mfma_f32_16x16x32_bf16(afrag[0][1], b1, c0, 0, 0, 0);
      c0 = __builtin_amdgcn_mfma_f32_16x16x32_bf16(afrag[0][2], b2, c0, 0, 0, 0);
      c1 = __builtin_amdgcn_mfma_f32_16x16x32_bf16(afrag[1][0], b0, c1, 0, 0, 0);
      c1 = __builtin_amdgcn_mfma_f32_16x16x32_bf16(afrag[1][1], b1, c1, 0, 0, 0);
      c1 = __builtin_amdgcn_mfma_f32_16x16x32_bf16(afrag[1][2], b2, c1, 0, 0, 0);
      int ijn = kl % 196, mk = kl / 196;         // interleaved store position
      // C/D layout: col = lane&15 (=kl), row = quad*4 + r (=q)  [m89]
#pragma unroll
      for (int r = 0; r < 4; ++r) {
        int q0 = quad*4 + r;                     // 0..15, all valid
        contl[q0][ijn*4 + mk] = __float2bfloat16(exp2f(c0[r]*kK2 - kCc));
        int q1 = 16 + quad*4 + r;                // 16..31, valid < 28
        if (q1 < kQR)
          contl[q1][ijn*4 + mk] = __float2bfloat16(exp2f(c1[r]*kK2 - kCc));
      }
    }
  }

  // ---- per-query bias tables (exp2 domain)
  for (int t = tid; t < kQR*58; t += 256) {
    int q = t / 58, s = t - q*58;
    float acc = 0.f;
    if (s < 27) {
#pragma unroll
      for (int c = 0; c < 32; ++c) acc += qs[q][c] * frowS[s*32 + c];
      Arr2[q][s] = acc;
    } else if (s < 54) {
      int n = s - 27;
#pragma unroll
      for (int c = 0; c < 32; ++c) acc += qs[q][32+c] * fcolS[n*32 + c];
      Acl2[q][n] = acc;
    } else {
      int p = s - 54;
#pragma unroll
      for (int c = 0; c < 32; ++c) acc += qs[q][64+c] * gembS[p*32 + c];
      AgE[q][p] = exp2f(acc);
    }
  }
  __syncthreads();

  const int kk = (tid < 196) ? (tid / 14) : 0;
  const int ll = (tid < 196) ? (tid % 14) : 0;
  const int da = kk - qi;

  for (int v = 0; v < 4; ++v) {
    int s1a, s1b, s2a, s2b;
    if (v == 0)      { s1a = 1;  s1b = 0;  s2a = 0;  s2b = 1;  }
    else if (v == 1) { s1a = 0;  s1b = -1; s2a = 1;  s2b = 0;  }
    else if (v == 2) { s1a = -1; s1b = 0;  s2a = 0;  s2b = -1; }
    else             { s1a = 0;  s1b = 1;  s2a = -1; s2b = 0;  }

    if (tid < 112) {
      int q = tid >> 2, m = tid & 3, gq = q / 7;
      AgErot[q][m] = AgE[q][(m - gq + v + 8) & 3];
    }
    __syncthreads();

    // ---- pass B: denominators. Vectorized contl read, ILP shuffle-reduce.
    float arvE[kQR];
    float prt[kQR];
    if (tid < 196) {
#pragma unroll
      for (int gq = 0; gq < 4; ++gq) {
#pragma unroll
        for (int jq = 0; jq < 7; ++jq) {
          const int q = gq*7 + jq;
          const int db = ll - (jhalf*7 + jq);
          const int ai = s1a*da + s1b*db, ci = s2a*da + s2b*db;
          arvE[q] = exp2f(Arr2[q][13 + ai] + Acl2[q][13 + ci]);
          ushort4 u = *(const ushort4*)(&contl[q][tid*4]);
          float e0 = __uint_as_float((unsigned)u.x << 16);
          float e1 = __uint_as_float((unsigned)u.y << 16);
          float e2 = __uint_as_float((unsigned)u.z << 16);
          float e3 = __uint_as_float((unsigned)u.w << 16);
          prt[q] = (e0*AgErot[q][0] + e1*AgErot[q][1] +
                    e2*AgErot[q][2] + e3*AgErot[q][3]) * arvE[q];
        }
      }
    } else {
#pragma unroll
      for (int q = 0; q < kQR; ++q) { prt[q] = 0.f; arvE[q] = 0.f; }
    }
    // level-outer butterfly: 28 independent shuffles per level (ILP)
#pragma unroll
    for (int off = 1; off < 64; off <<= 1) {
#pragma unroll
      for (int q = 0; q < kQR; ++q)
        prt[q] += __shfl_xor(prt[q], off, 64);
    }
    if ((tid & 63) == 0) {
#pragma unroll
      for (int q = 0; q < kQR; ++q) redw[q][tid >> 6] = prt[q];
    }
    __syncthreads();
    if (tid < kQR)
      DinvS[tid] = 1.0f / (redw[tid][0] + redw[tid][1] + redw[tid][2] + redw[tid][3]);
    __syncthreads();

    // ---- pass C: normalized probs (no transcendentals), summed over g.
    // Stored bf16, row stride 800 (MFMA A-operand layout for k_pv).
    if (tid < 196) {
      __hip_bfloat16* pbase =
          Pb + ((size_t)((bh*4 + v)*kSS + qi*14 + jhalf*7))*kKeyP + tid;
#pragma unroll
      for (int jq = 0; jq < 7; ++jq) {
        float am[4] = {0.f, 0.f, 0.f, 0.f};
#pragma unroll
        for (int gq = 0; gq < 4; ++gq) {
          const int q = gq*7 + jq;
          const float fq = arvE[q] * DinvS[q];
          ushort4 u = *(const ushort4*)(&contl[q][tid*4]);
          float e0 = __uint_as_float((unsigned)u.x << 16);
          float e1 = __uint_as_float((unsigned)u.y << 16);
          float e2 = __uint_as_float((unsigned)u.z << 16);
          float e3 = __uint_as_float((unsigned)u.w << 16);
          am[0] += e0 * (AgErot[q][0] * fq);
          am[1] += e1 * (AgErot[q][1] * fq);
          am[2] += e2 * (AgErot[q][2] * fq);
          am[3] += e3 * (AgErot[q][3] * fq);
        }
        __hip_bfloat16* pp = pbase + (size_t)jq*kKeyP;
#pragma unroll
        for (int m = 0; m < 4; ++m) pp[m*196] = __float2bfloat16(am[m]);
      }
    }
    // zero the key-pad [784,800) of this block's 7 rows for this v
    if (tid < 112) {
      int jq = tid >> 4, kp = tid & 15;
      Pb[((size_t)((bh*4 + v)*kSS + qi*14 + jhalf*7 + jq))*kKeyP + kKey + kp] =
          __float2bfloat16(0.f);
    }
    __syncthreads();   // protects AgErot for next v
  }
}

// ============================================================
// Kernel 3: PV + per-head partial output projection, atomically accumulated.
// Block = (bh, mt): 784 blocks x 128 thr -> ~3 blocks/CU (vs R9's 98 blocks
// at 1/CU -- the 71 us was pure latency starvation at occupancy 3.8%).
// Phase A: vo_h[16x96] = P[16x800] . V[800x96] -> bf16 LDS (R7-proven body).
// Phase B: partial out[16x96] = vo_h . Woh[h]^T (+ bo if h==0), atomicAdd.
// fp32 atomic sum of 8 head partials ~= R9's single 768-long bf16 MFMA sum.
// ============================================================
__global__ __launch_bounds__(128)
void k_pv(const __hip_bfloat16* __restrict__ Pb,
          const __hip_bfloat16* __restrict__ Vb,
          const __hip_bfloat16* __restrict__ Woh,
          const float* __restrict__ bo, float* __restrict__ out) {
  const int tid  = threadIdx.x;
  const int lane = tid & 63;
  const int wave = tid >> 6;
  const int bh = blockIdx.x / 49;
  const int mt = blockIdx.x % 49;
  const int mrow = lane & 15;
  const int quad = lane >> 4;
  const int b_ = bh >> 3, h_ = bh & 7;

  __shared__ alignas(16) __hip_bfloat16 vos[16][104];  // [m-row][c], pad 96->104

  // ---- phase A: PV (this head), 6 N-tiles split 3 per wave
  {
    const short* Ap = (const short*)Pb +
        ((size_t)(bh*kKey + mt*16 + mrow))*kKeyP + quad*8;
    const short* Bp = (const short*)Vb + ((size_t)bh*96)*kKeyP + quad*8;

    f32x4 acc0 = {0.f,0.f,0.f,0.f};
    f32x4 acc1 = {0.f,0.f,0.f,0.f};
    f32x4 acc2 = {0.f,0.f,0.f,0.f};
    const int n0 = (wave*3 + 0)*16 + mrow;
    const int n1 = (wave*3 + 1)*16 + mrow;
    const int n2 = (wave*3 + 2)*16 + mrow;

    for (int ks = 0; ks < kKeyP/32; ++ks) {
      bf16x8 a  = *(const bf16x8*)(Ap + ks*32);
      bf16x8 b0 = *(const bf16x8*)(Bp + (size_t)n0*kKeyP + ks*32);
      bf16x8 b1 = *(const bf16x8*)(Bp + (size_t)n1*kKeyP + ks*32);
      bf16x8 b2 = *(const bf16x8*)(Bp + (size_t)n2*kKeyP + ks*32);
      acc0 = __builtin_amdgcn_mfma_f32_16x16x32_bf16(a, b0, acc0, 0, 0, 0);
      acc1 = __builtin_amdgcn_mfma_f32_16x16x32_bf16(a, b1, acc1, 0, 0, 0);
      acc2 = __builtin_amdgcn_mfma_f32_16x16x32_bf16(a, b2, acc2, 0, 0, 0);
    }
    // C/D: col = lane&15 (= c within n-tile), row = quad*4 + r (= m-row)
#pragma unroll
    for (int r = 0; r < 4; ++r) {
      vos[quad*4 + r][n0] = __float2bfloat16(acc0[r]);
      vos[quad*4 + r][n1] = __float2bfloat16(acc1[r]);
      vos[quad*4 + r][n2] = __float2bfloat16(acc2[r]);
    }
  }
  __syncthreads();

  // ---- phase B: partial outproj for this head, 6 d-tiles split 3 per wave
  const short* wb = (const short*)Woh + (size_t)h_*9216;
#pragma unroll
  for (int w = 0; w < 3; ++w) {
    const int dt = wave*3 + w;
    f32x4 acc = {0.f,0.f,0.f,0.f};
#pragma unroll
    for (int ks = 0; ks < 3; ++ks) {
      bf16x8 a  = *(const bf16x8*)(&vos[mrow][ks*32 + quad*8]);
      bf16x8 bf = *(const bf16x8*)(wb + (size_t)(dt*16 + mrow)*96 + ks*32 + quad*8);
      acc = __builtin_amdgcn_mfma_f32_16x16x32_bf16(a, bf, acc, 0, 0, 0);
    }
    const int d = dt*16 + mrow;                 // D col = lane&15 = d-in-tile
    const float bias = (h_ == 0) ? bo[d] : 0.f;
#pragma unroll
    for (int r = 0; r < 4; ++r) {
      int m = mt*16 + quad*4 + r;
      int v = m / kSS, ij = m - v*kSS;
      atomicAdd(&out[((size_t)(b_*96 + d)*4 + v)*kSS + ij], acc[r] + bias);
    }
  }
}

// ============================================================
extern "C" void kernel_launch(void* const* d_in, const int* in_sizes, int n_in,
                              void* d_out, int out_size, void* d_ws, size_t ws_size,
                              hipStream_t stream) {
  const float* x    = (const float*)d_in[0];
  const float* Wq   = (const float*)d_in[1];
  const float* bq   = (const float*)d_in[2];
  const float* Wk   = (const float*)d_in[3];
  const float* bk   = (const float*)d_in[4];
  const float* Wv   = (const float*)d_in[5];
  const float* bv   = (const float*)d_in[6];
  const float* Wo   = (const float*)d_in[7];
  const float* bo   = (const float*)d_in[8];
  const float* rw1  = (const float*)d_in[9];
  const float* rb1  = (const float*)d_in[10];
  const float* rgam = (const float*)d_in[11];
  const float* rbet = (const float*)d_in[12];
  const float* rw2  = (const float*)d_in[13];
  const float* rb2  = (const float*)d_in[14];
  const float* cw1  = (const float*)d_in[15];
  const float* cb1  = (const float*)d_in[16];
  const float* cgam = (const float*)d_in[17];
  const float* cbet = (const float*)d_in[18];
  const float* cw2  = (const float*)d_in[19];
  const float* cb2  = (const float*)d_in[20];
  const float* gemb = (const float*)d_in[21];
  // d_in[22..24] = row_rel, col_rel, g_idx: reconstructed analytically.

  float* ws = (float*)d_ws;
  __hip_bfloat16* Qb = (__hip_bfloat16*)(ws + OFF_Qb);
  __hip_bfloat16* Kb = (__hip_bfloat16*)(ws + OFF_Kb);
  __hip_bfloat16* Vb = (__hip_bfloat16*)(ws + OFF_V);
  float* Frow = ws + OFF_FR;
  float* Fcol = ws + OFF_FC;
  __hip_bfloat16* Pb = (__hip_bfloat16*)(ws + OFF_PS);
  __hip_bfloat16* Woh = (__hip_bfloat16*)(ws + OFF_WOH);
  float* out  = (float*)d_out;

  k_qkv<<<dim3(112, 3), 256, 0, stream>>>(x, Wq, bq, Wk, bk, Wv, bv, Qb, Kb, Vb,
                                          rw1, rb1, rgam, rbet, rw2, rb2,
                                          cw1, cb1, cgam, cbet, cw2, cb2,
                                          Frow, Fcol, Wo, Woh, out);
  k_attn<<<448, 256, 0, stream>>>(Qb, Kb, Frow, Fcol, gemb, Pb);
  k_pv<<<784, 128, 0, stream>>>(Pb, Vb, Woh, bo, out);
}